// Round 9
// baseline (1127.825 us; speedup 1.0000x reference)
//
#include <hip/hip_runtime.h>
#include <hip/hip_bf16.h>

#define B_ 2
#define C_ 128
#define HX_ 64
#define HY_ 64
#define HZ_ 32
#define N_ 131072
#define M_ 64
#define G_ 32
#define SCALE_ 0.17677669529663687f  // 1/sqrt(32)

typedef unsigned short u16;
typedef __bf16 bf16x8 __attribute__((ext_vector_type(8)));
typedef float f32x4 __attribute__((ext_vector_type(4)));

#define MFMA(a, b, c) __builtin_amdgcn_mfma_f32_16x16x32_bf16(a, b, c, 0, 0, 0)

__device__ __forceinline__ float bf2f(u16 u){
    return __uint_as_float(((unsigned int)u) << 16);
}
__device__ __forceinline__ u16 f2bf(float f){
    unsigned int u = __float_as_uint(f);
    unsigned int r = (u + 0x7FFFu + ((u >> 16) & 1u)) >> 16;
    return (u16)r;
}
__device__ __forceinline__ bf16x8 ldf(const u16* p){
    return __builtin_bit_cast(bf16x8, *reinterpret_cast<const uint4*>(p));
}
__device__ __forceinline__ float wred_sum(float v){
    for (int o = 32; o; o >>= 1) v += __shfl_xor(v, o);
    return v;
}

// ---------------- weight conversion to bf16 ----------------
__global__ __launch_bounds__(256) void k_wcvt(const float* __restrict__ pw, const float* __restrict__ g1w,
        const float* __restrict__ in_w, const float* __restrict__ out_w, const float* __restrict__ g2w,
        u16* __restrict__ wA, u16* __restrict__ wKV, u16* __restrict__ wQ, u16* __restrict__ wO, u16* __restrict__ wG2){
    int idx = blockIdx.x*256 + threadIdx.x;
    if (idx < 32768){
        int j = idx >> 7, k = idx & 127;
        wA[idx] = f2bf(j < 128 ? pw[j*128 + k] : g1w[(j-128)*128 + k]);
    } else if (idx < 131072){
        int r = idx - 32768;
        int a = r >> 15, jk = r & 32767;
        int j = jk >> 7, k = jk & 127;
        wKV[r] = f2bf(in_w[((size_t)a*384 + 128 + j)*128 + k]);
    } else if (idx < 147456){
        int r = idx - 131072;
        wQ[r] = f2bf(in_w[4*384*128 + r]);
    } else if (idx < 163840){
        int r = idx - 147456;
        wO[r] = f2bf(out_w[4*128*128 + r]);
    } else if (idx < 180224){
        int r = idx - 163840;
        wG2[r] = f2bf(g2w[r]);
    }
}

// ---------------- depthwise conv3d, float4-vectorized z-sliding + group stats ----------------
__global__ __launch_bounds__(256, 2) void k_conv3(const float* __restrict__ h,
        const float* __restrict__ dw_w, u16* __restrict__ ybf, u16* __restrict__ hb16,
        float* __restrict__ gstats){
    int t = threadIdx.x;
    int lane = t & 31;            // channel quad == GN group
    int c4 = lane << 2;
    int xg = t >> 5;              // 0..7
    int bi = blockIdx.x;          // [0, B*64*8)
    int b = bi >> 9;
    int y = (bi >> 3) & 63;
    int x = ((bi & 7) << 3) | xg;
    const float* hb = h + (size_t)b*N_*C_;
    u16* yb = ybf + (size_t)b*N_*C_;
    u16* hbb = hb16 + (size_t)b*N_*C_;
    f32x4 wv[27];
    int off[9];
    #pragma unroll
    for (int dxi = 0; dxi < 3; ++dxi){
        #pragma unroll
        for (int dyi = 0; dyi < 3; ++dyi){
            int xr = x + dxi - 1, yr = y + dyi - 1;
            float m = (xr >= 0 && xr < HX_ && yr >= 0 && yr < HY_) ? 1.f : 0.f;
            int xx = min(max(xr, 0), HX_-1);
            int yy = min(max(yr, 0), HY_-1);
            off[dxi*3+dyi] = (yy*64 + xx)*128 + c4;
            #pragma unroll
            for (int dzi = 0; dzi < 3; ++dzi){
                int k = (dxi*3+dyi)*3+dzi;
                int wk = dxi*9 + dyi*3 + dzi;
                f32x4 wq;
                #pragma unroll
                for (int e = 0; e < 4; ++e) wq[e] = dw_w[(c4+e)*27 + wk] * m;
                wv[k] = wq;
            }
        }
    }
    f32x4 accA = {0,0,0,0}, accB = {0,0,0,0}, accC = {0,0,0,0};
    f32x4 sum4 = {0,0,0,0}, ss4 = {0,0,0,0};
    #pragma unroll 2
    for (int zp = 0; zp < 32; ++zp){
        size_t zb = (size_t)zp*524288;
        f32x4 v[9];
        #pragma unroll
        for (int j = 0; j < 9; ++j) v[j] = *(const f32x4*)(hb + zb + off[j]);
        {
            unsigned int p0 = (unsigned int)f2bf(v[4][0]) | ((unsigned int)f2bf(v[4][1]) << 16);
            unsigned int p1 = (unsigned int)f2bf(v[4][2]) | ((unsigned int)f2bf(v[4][3]) << 16);
            uint2 pk = {p0, p1};
            *(uint2*)(hbb + zb + off[4]) = pk;
        }
        f32x4 s0 = {0,0,0,0}, s1 = {0,0,0,0}, s2 = {0,0,0,0};
        #pragma unroll
        for (int j = 0; j < 9; ++j){
            s0 += v[j]*wv[j*3+0];
            s1 += v[j]*wv[j*3+1];
            s2 += v[j]*wv[j*3+2];
        }
        accA += s2; accB += s1; accC += s0;
        if (zp >= 1){
            f32x4 yv = accA;
            sum4 += yv; ss4 += yv*yv;
            unsigned int p0 = (unsigned int)f2bf(yv[0]) | ((unsigned int)f2bf(yv[1]) << 16);
            unsigned int p1 = (unsigned int)f2bf(yv[2]) | ((unsigned int)f2bf(yv[3]) << 16);
            uint2 pk = {p0, p1};
            *(uint2*)(yb + (size_t)(zp-1)*524288 + off[4]) = pk;
        }
        accA = accB; accB = accC; accC = (f32x4){0,0,0,0};
    }
    {
        f32x4 yv = accA;   // out(31)
        sum4 += yv; ss4 += yv*yv;
        unsigned int p0 = (unsigned int)f2bf(yv[0]) | ((unsigned int)f2bf(yv[1]) << 16);
        unsigned int p1 = (unsigned int)f2bf(yv[2]) | ((unsigned int)f2bf(yv[3]) << 16);
        uint2 pk = {p0, p1};
        *(uint2*)(yb + (size_t)31*524288 + off[4]) = pk;
    }
    float sum = sum4[0]+sum4[1]+sum4[2]+sum4[3];
    float ss  = ss4[0]+ss4[1]+ss4[2]+ss4[3];
    sum += __shfl_xor(sum, 32);
    ss  += __shfl_xor(ss, 32);
    if ((t & 32) == 0){
        atomicAdd(&gstats[(b*G_ + lane)*2 + 0], sum);
        atomicAdd(&gstats[(b*G_ + lane)*2 + 1], ss);
    }
}

__global__ void k_gstats_fin(const float* __restrict__ gstats, float* __restrict__ gfin){
    int t = threadIdx.x;
    if (t < B_*G_){
        const float cnt = 4.f * (float)N_;
        float mean = gstats[t*2] / cnt;
        float var  = gstats[t*2+1] / cnt - mean*mean;
        gfin[t*2]   = mean;
        gfin[t*2+1] = rsqrtf(var + 1e-5f);
    }
}

// ---------------- stage A: GN+GELU (fused) + pointwise + gate1 via MFMA ----------------
__global__ __launch_bounds__(256) void k_stageA(const u16* __restrict__ ybf, const u16* __restrict__ hb16,
        const float* __restrict__ gfin, const float* __restrict__ gn_w, const float* __restrict__ gn_b,
        const float* __restrict__ g1b, const float* __restrict__ s1p,
        const u16* __restrict__ wA, u16* __restrict__ h1b){
    __shared__ __align__(16) u16 sU[64*136];
    __shared__ __align__(16) u16 sH[64*136];
    __shared__ float sPar[384];
    int t = threadIdx.x;
    int w = t >> 6, l = t & 63, lm = l & 15, kq = l >> 4;
    if (t < 128){ sPar[t] = gn_w[t]; sPar[128+t] = gn_b[t]; sPar[256+t] = gfin[t]; }
    bf16x8 wUf[2][4], wGf[2][4];
    float gbias[2];
    #pragma unroll
    for (int jt = 0; jt < 2; ++jt){
        int j = w*32 + jt*16 + lm;
        gbias[jt] = g1b[j];
        #pragma unroll
        for (int ks = 0; ks < 4; ++ks){
            wUf[jt][ks] = ldf(wA + (size_t)j*128 + ks*32 + kq*8);
            wGf[jt][ks] = ldf(wA + (size_t)(128+j)*128 + ks*32 + kq*8);
        }
    }
    float s1 = s1p[0];
    __syncthreads();
    for (int it = 0; it < 4; ++it){
        int tile = blockIdx.x + it*1024;
        size_t r0 = (size_t)tile*64;
        int bsel = (tile >= 2048) ? 1 : 0;
        for (int pass = 0; pass < 4; ++pass){
            int cid = pass*256 + t;
            int row = cid >> 4, col8 = (cid & 15)*8;
            size_t gi = (r0 + row)*C_ + col8;
            uint4 yraw = *(const uint4*)(ybf + gi);
            uint4 hraw = *(const uint4*)(hb16 + gi);
            const u16* yp = (const u16*)&yraw;
            unsigned int pu[4];
            #pragma unroll
            for (int p2 = 0; p2 < 4; ++p2){
                u16 r2[2];
                #pragma unroll
                for (int e2 = 0; e2 < 2; ++e2){
                    int e = p2*2 + e2;
                    int ch = col8 + e;
                    int g = ch >> 2;
                    float mean = sPar[256 + (bsel*32+g)*2];
                    float inv  = sPar[256 + (bsel*32+g)*2 + 1];
                    float v = (bf2f(yp[e]) - mean)*inv*sPar[ch] + sPar[128+ch];
                    float u = 0.5f*v*(1.f + erff(v*0.70710678118654752f));
                    r2[e2] = f2bf(u);
                }
                pu[p2] = (unsigned int)r2[0] | ((unsigned int)r2[1] << 16);
            }
            *(uint4*)(sU + row*136 + col8) = *(uint4*)pu;
            *(uint4*)(sH + row*136 + col8) = hraw;
        }
        __syncthreads();
        f32x4 accU[4][2], accG[4][2];
        #pragma unroll
        for (int rt = 0; rt < 4; ++rt)
            #pragma unroll
            for (int jt = 0; jt < 2; ++jt){
                accU[rt][jt] = (f32x4){0.f,0.f,0.f,0.f};
                accG[rt][jt] = (f32x4){gbias[jt],gbias[jt],gbias[jt],gbias[jt]};
            }
        #pragma unroll
        for (int rt = 0; rt < 4; ++rt)
            #pragma unroll
            for (int ks = 0; ks < 4; ++ks){
                bf16x8 aU = ldf(sU + (rt*16+lm)*136 + ks*32 + kq*8);
                bf16x8 aH = ldf(sH + (rt*16+lm)*136 + ks*32 + kq*8);
                #pragma unroll
                for (int jt = 0; jt < 2; ++jt){
                    accU[rt][jt] = MFMA(aU, wUf[jt][ks], accU[rt][jt]);
                    accG[rt][jt] = MFMA(aH, wGf[jt][ks], accG[rt][jt]);
                }
            }
        #pragma unroll
        for (int rt = 0; rt < 4; ++rt)
            #pragma unroll
            for (int jt = 0; jt < 2; ++jt){
                int col = w*32 + jt*16 + lm;
                #pragma unroll
                for (int r = 0; r < 4; ++r){
                    int lrow = rt*16 + kq*4 + r;
                    float g = 1.f/(1.f + expf(-accG[rt][jt][r]));
                    float hv = bf2f(sH[lrow*136 + col]);
                    float h1v = hv + s1*g*accU[rt][jt][r];
                    h1b[(r0 + lrow)*C_ + col] = f2bf(h1v);
                }
            }
        __syncthreads();
    }
}

// ---------------- axis attention Q projection (tiny, fp32) ----------------
__global__ __launch_bounds__(256) void k_qh_axes(const float* __restrict__ gtok,
        const float* __restrict__ in_w, const float* __restrict__ in_b, float* __restrict__ qhT){
    int idx = blockIdx.x*256 + threadIdx.x;   // [0, 3*128*64)
    int m = idx & 63;
    int hd = (idx >> 6) & 127;
    int a = idx >> 13;
    float acc = in_b[a*384 + hd];
    const float* w = in_w + ((size_t)a*384 + hd)*C_;
    const float* q = gtok + (size_t)m*C_;
    for (int c = 0; c < C_; ++c) acc += q[c]*w[c];
    qhT[idx] = acc;
}

// ---------------- axis attentions: full-MFMA (kvproj + QK^T + PV) ----------------
template<int AXIS, int L, int S>
__global__ __launch_bounds__(256, 2) void k_axis_attn(const u16* __restrict__ h1b,
        const u16* __restrict__ wKVb, const float* __restrict__ in_b,
        const float* __restrict__ qhT, float* __restrict__ o_mean){
    constexpr int SLICES = 8;
    constexpr int PARTS = S / SLICES;
    constexpr int PSROW = L + 8;
    constexpr int PSZ = 64 * PSROW;
    constexpr int NT = L / 16;
    constexpr int KS = L / 32;
    __shared__ __align__(16) u16 sm[6*PSZ];
    int t = threadIdx.x;
    int w = t >> 6, l = t & 63, lm = l & 15, kq = l >> 4;
    int b = blockIdx.x / PARTS;
    int part = blockIdx.x % PARTS;
    u16* rows = sm;
    u16* kv   = sm + 2*PSZ;
    u16* vT   = sm + 4*PSZ;
    u16* Ps   = sm + w*PSZ;
    bf16x8 wf[4][4];
    float bias[4];
    #pragma unroll
    for (int jt = 0; jt < 4; ++jt){
        int j = w*64 + jt*16 + lm;
        bias[jt] = in_b[AXIS*384 + 128 + j];
        #pragma unroll
        for (int ks = 0; ks < 4; ++ks)
            wf[jt][ks] = ldf(wKVb + ((size_t)AXIS*256 + j)*128 + ks*32 + kq*8);
    }
    bf16x8 qf[4];
    #pragma unroll
    for (int mt = 0; mt < 4; ++mt){
        union { u16 u[8]; bf16x8 v; } tmp;
        #pragma unroll
        for (int e = 0; e < 8; ++e)
            tmp.u[e] = f2bf(qhT[(AXIS*C_ + w*32 + kq*8 + e)*64 + mt*16 + lm] * SCALE_);
        qf[mt] = tmp.v;
    }
    f32x4 oacc[4][2];
    #pragma unroll
    for (int mt = 0; mt < 4; ++mt)
        #pragma unroll
        for (int dt = 0; dt < 2; ++dt)
            oacc[mt][dt] = (f32x4){0.f,0.f,0.f,0.f};
    const u16* hb = h1b + (size_t)b*N_*C_;
    for (int si = 0; si < SLICES; ++si){
        int s = part*SLICES + si;
        for (int ci = t; ci < L*16; ci += 256){
            int p = ci >> 4, c8 = (ci & 15)*8;
            int n;
            if (AXIS == 0){ int yy = s >> 5, zz = s & 31; n = zz*4096 + yy*64 + p; }
            else if (AXIS == 1){ int xx = s >> 5, zz = s & 31; n = zz*4096 + p*64 + xx; }
            else { int xx = s >> 6, yy = s & 63; n = p*4096 + yy*64 + xx; }
            *(uint4*)(rows + p*136 + c8) = *(const uint4*)(hb + (size_t)n*C_ + c8);
        }
        __syncthreads();
        #pragma unroll
        for (int rt = 0; rt < NT; ++rt){
            f32x4 acc[4];
            #pragma unroll
            for (int jt = 0; jt < 4; ++jt) acc[jt] = (f32x4){bias[jt],bias[jt],bias[jt],bias[jt]};
            #pragma unroll
            for (int ks = 0; ks < 4; ++ks){
                bf16x8 a = ldf(rows + (rt*16+lm)*136 + ks*32 + kq*8);
                #pragma unroll
                for (int jt = 0; jt < 4; ++jt) acc[jt] = MFMA(a, wf[jt][ks], acc[jt]);
            }
            #pragma unroll
            for (int jt = 0; jt < 4; ++jt){
                int j = w*64 + jt*16 + lm;
                #pragma unroll
                for (int r = 0; r < 4; ++r){
                    int key = rt*16 + kq*4 + r;
                    if (w < 2) kv[key*136 + j] = f2bf(acc[jt][r]);
                    else       vT[(j-128)*PSROW + key] = f2bf(acc[jt][r]);
                }
            }
        }
        __syncthreads();
        f32x4 lacc[4][NT];
        #pragma unroll
        for (int mt = 0; mt < 4; ++mt)
            #pragma unroll
            for (int nt = 0; nt < NT; ++nt) lacc[mt][nt] = (f32x4){0.f,0.f,0.f,0.f};
        #pragma unroll
        for (int nt = 0; nt < NT; ++nt){
            bf16x8 kf = ldf(kv + (nt*16+lm)*136 + w*32 + kq*8);
            #pragma unroll
            for (int mt = 0; mt < 4; ++mt) lacc[mt][nt] = MFMA(qf[mt], kf, lacc[mt][nt]);
        }
        __syncthreads();
        #pragma unroll
        for (int mt = 0; mt < 4; ++mt){
            #pragma unroll
            for (int r = 0; r < 4; ++r){
                float mx = lacc[mt][0][r];
                #pragma unroll
                for (int nt = 1; nt < NT; ++nt) mx = fmaxf(mx, lacc[mt][nt][r]);
                mx = fmaxf(mx, __shfl_xor(mx,1));
                mx = fmaxf(mx, __shfl_xor(mx,2));
                mx = fmaxf(mx, __shfl_xor(mx,4));
                mx = fmaxf(mx, __shfl_xor(mx,8));
                float ev[NT]; float sum = 0.f;
                #pragma unroll
                for (int nt = 0; nt < NT; ++nt){ ev[nt] = expf(lacc[mt][nt][r] - mx); sum += ev[nt]; }
                sum += __shfl_xor(sum,1);
                sum += __shfl_xor(sum,2);
                sum += __shfl_xor(sum,4);
                sum += __shfl_xor(sum,8);
                float inv = 1.f/sum;
                #pragma unroll
                for (int nt = 0; nt < NT; ++nt)
                    Ps[(mt*16 + kq*4 + r)*PSROW + nt*16 + lm] = f2bf(ev[nt]*inv);
            }
        }
        #pragma unroll
        for (int ks = 0; ks < KS; ++ks){
            bf16x8 vb[2];
            #pragma unroll
            for (int dt = 0; dt < 2; ++dt)
                vb[dt] = ldf(vT + (w*32 + dt*16 + lm)*PSROW + ks*32 + kq*8);
            #pragma unroll
            for (int mt = 0; mt < 4; ++mt){
                bf16x8 pa = ldf(Ps + (mt*16+lm)*PSROW + ks*32 + kq*8);
                #pragma unroll
                for (int dt = 0; dt < 2; ++dt)
                    oacc[mt][dt] = MFMA(pa, vb[dt], oacc[mt][dt]);
            }
        }
        __syncthreads();
    }
    const float invS = 1.f / (float)S;
    float* om = o_mean + (size_t)(AXIS*B_ + b)*M_*C_;
    #pragma unroll
    for (int mt = 0; mt < 4; ++mt)
        #pragma unroll
        for (int dt = 0; dt < 2; ++dt)
            #pragma unroll
            for (int r = 0; r < 4; ++r){
                int m = mt*16 + kq*4 + r;
                int d = dt*16 + lm;
                atomicAdd(&om[m*C_ + w*32 + d], oacc[mt][dt][r]*invS);
            }
}

// ---------------- token chain (small, fp32) ----------------
__global__ __launch_bounds__(256) void k_tokens(const float* __restrict__ o_mean,
        const float* __restrict__ out_w, const float* __restrict__ out_b, float* __restrict__ tokens){
    int idx = blockIdx.x*256 + threadIdx.x;  // [0, B*M*C)
    int c = idx & 127;
    int m = (idx >> 7) & 63;
    int b = idx >> 13;
    float acc = 0.f;
    for (int a = 0; a < 3; ++a){
        const float* om = o_mean + ((size_t)(a*B_ + b)*M_ + m)*C_;
        const float* w = out_w + ((size_t)a*C_ + c)*C_;
        float s = out_b[a*C_ + c];
        for (int k = 0; k < C_; ++k) s += om[k]*w[k];
        acc += s;
    }
    tokens[idx] = acc;
}

__global__ __launch_bounds__(128) void k_ln(const float* __restrict__ in,
        const float* __restrict__ w, const float* __restrict__ b, float* __restrict__ out){
    int r = blockIdx.x;
    int c = threadIdx.x;
    float v = in[(size_t)r*C_ + c];
    __shared__ float red[4];
    float s = wred_sum(v), ss = wred_sum(v*v);
    int wv = c >> 6;
    if ((c & 63) == 0){ red[wv*2] = s; red[wv*2+1] = ss; }
    __syncthreads();
    float S = red[0] + red[2], SS = red[1] + red[3];
    float mean = S / 128.f;
    float var = SS / 128.f - mean*mean;
    out[(size_t)r*C_ + c] = (v - mean) * rsqrtf(var + 1e-5f) * w[c] + b[c];
}

__global__ __launch_bounds__(256) void k_qkv3(const float* __restrict__ t_in,
        const float* __restrict__ in_w, const float* __restrict__ in_b, float* __restrict__ qkv3){
    int idx = blockIdx.x*256 + threadIdx.x;  // [0, B*M*384)
    int j = idx % 384;
    int m = (idx / 384) & 63;
    int b = idx / (384*64);
    const float* x = t_in + ((size_t)b*64 + m)*C_;
    const float* w = in_w + ((size_t)3*384 + j)*C_;
    float acc = in_b[3*384 + j];
    for (int c = 0; c < C_; ++c) acc += x[c]*w[c];
    qkv3[idx] = acc;
}

__global__ __launch_bounds__(64) void k_attn3(const float* __restrict__ qkv3, float* __restrict__ o3){
    int b = blockIdx.x >> 2, hh = blockIdx.x & 3;
    int m = threadIdx.x;
    const float* base = qkv3 + (size_t)b*64*384;
    float q[32];
    #pragma unroll
    for (int d = 0; d < 32; ++d) q[d] = base[m*384 + hh*32 + d];
    float lg[64]; float mx = -1e30f;
    for (int mk = 0; mk < 64; ++mk){
        float acc = 0.f;
        #pragma unroll
        for (int d = 0; d < 32; ++d) acc += q[d] * base[mk*384 + 128 + hh*32 + d];
        acc *= SCALE_;
        lg[mk] = acc; mx = fmaxf(mx, acc);
    }
    float sum = 0.f;
    #pragma unroll
    for (int mk = 0; mk < 64; ++mk){ float e = expf(lg[mk]-mx); lg[mk] = e; sum += e; }
    float inv = 1.f/sum;
    float o[32];
    #pragma unroll
    for (int d = 0; d < 32; ++d) o[d] = 0.f;
    for (int mk = 0; mk < 64; ++mk){
        float al = lg[mk]*inv;
        #pragma unroll
        for (int d = 0; d < 32; ++d) o[d] += al * base[mk*384 + 256 + hh*32 + d];
    }
    #pragma unroll
    for (int d = 0; d < 32; ++d) o3[((size_t)b*64 + m)*C_ + hh*32 + d] = o[d];
}

__global__ __launch_bounds__(256) void k_tokens2(const float* __restrict__ o3,
        const float* __restrict__ out_w, const float* __restrict__ out_b, float* __restrict__ tokens2){
    int idx = blockIdx.x*256 + threadIdx.x;
    int c = idx & 127;
    int m = (idx >> 7) & 63;
    int b = idx >> 13;
    const float* x = o3 + ((size_t)b*64 + m)*C_;
    const float* w = out_w + ((size_t)3*C_ + c)*C_;
    float acc = out_b[3*C_ + c];
    for (int k = 0; k < C_; ++k) acc += x[k]*w[k];
    tokens2[idx] = acc;
}

// kh: [b][h][key][32d] bf16, pre-scaled by SCALE_.  vh: [b][key][128] bf16.
__global__ __launch_bounds__(256) void k_kv4(const float* __restrict__ tokens2,
        const float* __restrict__ in_w, const float* __restrict__ in_b,
        u16* __restrict__ khs, u16* __restrict__ vhb){
    int idx = blockIdx.x*256 + threadIdx.x;   // [0, B*16384)
    int b = idx >> 14;
    int r = idx & 16383;
    if (r < 8192){
        int hh = r >> 11, key = (r >> 5) & 63, d = r & 31;
        int hd = hh*32 + d;
        const float* x = tokens2 + ((size_t)b*64 + key)*C_;
        const float* w = in_w + ((size_t)4*384 + 128 + hd)*C_;
        float acc = in_b[4*384 + 128 + hd];
        for (int c = 0; c < C_; ++c) acc += x[c]*w[c];
        khs[(size_t)b*8192 + r] = f2bf(acc * SCALE_);
    } else {
        int rr = r - 8192;
        int key = rr >> 7, c = rr & 127;
        const float* x = tokens2 + ((size_t)b*64 + key)*C_;
        const float* w = in_w + ((size_t)4*384 + 256 + c)*C_;
        float acc = in_b[4*384 + 256 + c];
        for (int k = 0; k < 128; ++k) acc += x[k]*w[k];
        vhb[(size_t)b*8192 + rr] = f2bf(acc);
    }
}

// ---------------- fused: LN -> Qproj -> attn -> outproj -> gate2 -> RMS mixture ----------------
// 512 threads = 2 independent 64-row tiles (waves 0-3 tile 0, waves 4-7 tile 1).
// __launch_bounds__(512, 2): 2 waves/EU -> VGPR cap 256, no spills, 1 block/CU (8 waves).
// Per-tile LDS (u16, 22016): X/QO [0,8704) ; H then h2(bf16, stride 132) [8704,17408) ; P [17408,22016)
__global__ __launch_bounds__(512, 2) void k_globfinal(const u16* __restrict__ h1b,
        const u16* __restrict__ wQb, const u16* __restrict__ wOb, const u16* __restrict__ wG2b,
        const u16* __restrict__ khs, const u16* __restrict__ vhb,
        const float* __restrict__ in_b, const float* __restrict__ out_b,
        const float* __restrict__ g2b, const float* __restrict__ s2p,
        const float* __restrict__ ln_w, const float* __restrict__ ln_b,
        const float* __restrict__ hist0, const float* __restrict__ hist1,
        const float* __restrict__ rms_w, const float* __restrict__ blk_w,
        float* __restrict__ outp){
    __shared__ __align__(16) u16 smb[44032];
    __shared__ float sLn[384];
    int t = threadIdx.x;
    int w8 = t >> 6;              // 0..7
    int ti = w8 >> 2;             // tile within block
    int wl = w8 & 3;              // wave within tile (= head)
    int l = t & 63, lm = l & 15, kq = l >> 4;
    int tt = t & 255;             // thread within tile
    u16* sm = smb + ti*22016;
    if (t < 128){ sLn[t] = ln_w[128+t]; sLn[128+t] = ln_b[128+t]; sLn[256+t] = blk_w[t]*rms_w[t]; }
    int b = blockIdx.x >> 9;
    bf16x8 wQf[2][4], wOf[2][4], wGf[2][4], khf[4], vf[2][2];
    float qb[2], ob[2], gb[2];
    #pragma unroll
    for (int jt = 0; jt < 2; ++jt){
        int j = wl*32 + jt*16 + lm;
        qb[jt] = in_b[4*384 + j];
        ob[jt] = out_b[4*128 + j];
        gb[jt] = g2b[j];
        #pragma unroll
        for (int ks = 0; ks < 4; ++ks){
            wQf[jt][ks] = ldf(wQb + (size_t)j*128 + ks*32 + kq*8);
            wOf[jt][ks] = ldf(wOb + (size_t)j*128 + ks*32 + kq*8);
            wGf[jt][ks] = ldf(wG2b + (size_t)j*128 + ks*32 + kq*8);
        }
    }
    #pragma unroll
    for (int jt = 0; jt < 4; ++jt)
        khf[jt] = ldf(khs + ((size_t)(b*4 + wl)*64 + jt*16 + lm)*32 + kq*8);
    #pragma unroll
    for (int jt = 0; jt < 2; ++jt)
        #pragma unroll
        for (int ks = 0; ks < 2; ++ks){
            union { u16 u[8]; bf16x8 v; } tmp;
            #pragma unroll
            for (int e = 0; e < 8; ++e){
                int key = ks*32 + kq*8 + e;
                tmp.u[e] = vhb[(size_t)(b*64 + key)*128 + wl*32 + jt*16 + lm];
            }
            vf[jt][ks] = tmp.v;
        }
    float s2 = s2p[0];
    __syncthreads();

    for (int it = 0; it < 2; ++it){
        int pair = (blockIdx.x & 511) + it*512;
        int tile = pair*2 + ti;
        size_t r0 = (size_t)b*N_ + (size_t)tile*64;
        // ---- stage h1 (raw -> H) + LN (-> X) ----
        {
            int r = tt >> 2, q = tt & 3;
            const u16* src = h1b + (r0 + r)*C_ + q*32;
            uint4 raw[4];
            float v[32];
            float s = 0.f, ss = 0.f;
            #pragma unroll
            for (int c4 = 0; c4 < 4; ++c4){
                raw[c4] = *(const uint4*)(src + c4*8);
                const u16* pu = (const u16*)&raw[c4];
                #pragma unroll
                for (int e = 0; e < 8; ++e){ float x = bf2f(pu[e]); v[c4*8+e] = x; s += x; ss += x*x; }
            }
            s += __shfl_xor(s,1); s += __shfl_xor(s,2);
            ss += __shfl_xor(ss,1); ss += __shfl_xor(ss,2);
            float mean = s*(1.f/128.f);
            float inv = rsqrtf(ss*(1.f/128.f) - mean*mean + 1e-5f);
            #pragma unroll
            for (int c4 = 0; c4 < 4; ++c4){
                unsigned int o[4];
                #pragma unroll
                for (int p2 = 0; p2 < 4; ++p2){
                    int c = q*32 + c4*8 + p2*2;
                    u16 a0 = f2bf((v[c4*8+p2*2]   - mean)*inv*sLn[c]   + sLn[128+c]);
                    u16 a1 = f2bf((v[c4*8+p2*2+1] - mean)*inv*sLn[c+1] + sLn[128+c+1]);
                    o[p2] = (unsigned int)a0 | ((unsigned int)a1 << 16);
                }
                *(uint4*)(sm + 0    + r*136 + q*32 + c4*8) = *(uint4*)o;
                *(uint4*)(sm + 8704 + r*136 + q*32 + c4*8) = raw[c4];
            }
        }
        __syncthreads();
        // ---- q projection (reads X) ----
        f32x4 accQ[4][2];
        #pragma unroll
        for (int rt = 0; rt < 4; ++rt)
            #pragma unroll
            for (int jt = 0; jt < 2; ++jt)
                accQ[rt][jt] = (f32x4){qb[jt],qb[jt],qb[jt],qb[jt]};
        #pragma unroll
        for (int rt = 0; rt < 4; ++rt)
            #pragma unroll
            for (int ks = 0; ks < 4; ++ks){
                bf16x8 a = ldf(sm + 0 + (rt*16+lm)*136 + ks*32 + kq*8);
                #pragma unroll
                for (int jt = 0; jt < 2; ++jt)
                    accQ[rt][jt] = MFMA(a, wQf[jt][ks], accQ[rt][jt]);
            }
        __syncthreads();   // all X reads done; X region becomes QO
        #pragma unroll
        for (int rt = 0; rt < 4; ++rt)
            #pragma unroll
            for (int jt = 0; jt < 2; ++jt)
                #pragma unroll
                for (int r = 0; r < 4; ++r)
                    sm[0 + (rt*16+kq*4+r)*136 + wl*32+jt*16+lm] = f2bf(accQ[rt][jt][r]);
        // ---- logits + softmax + PV (wave = head; QO cols wave-private) ----
        u16* Ps = sm + 17408 + wl*1152;
        #pragma unroll
        for (int mt = 0; mt < 4; ++mt){
            bf16x8 aq = ldf(sm + 0 + (mt*16+lm)*136 + wl*32 + kq*8);
            f32x4 lacc[4];
            #pragma unroll
            for (int jt = 0; jt < 4; ++jt) lacc[jt] = (f32x4){0.f,0.f,0.f,0.f};
            #pragma unroll
            for (int jt = 0; jt < 4; ++jt) lacc[jt] = MFMA(aq, khf[jt], lacc[jt]);
            #pragma unroll
            for (int r = 0; r < 4; ++r){
                float v0 = lacc[0][r], v1 = lacc[1][r], v2 = lacc[2][r], v3 = lacc[3][r];
                float mx = fmaxf(fmaxf(v0,v1), fmaxf(v2,v3));
                mx = fmaxf(mx, __shfl_xor(mx,1));
                mx = fmaxf(mx, __shfl_xor(mx,2));
                mx = fmaxf(mx, __shfl_xor(mx,4));
                mx = fmaxf(mx, __shfl_xor(mx,8));
                float e0 = expf(v0-mx), e1 = expf(v1-mx), e2 = expf(v2-mx), e3 = expf(v3-mx);
                float sum = e0+e1+e2+e3;
                sum += __shfl_xor(sum,1);
                sum += __shfl_xor(sum,2);
                sum += __shfl_xor(sum,4);
                sum += __shfl_xor(sum,8);
                float inv = 1.f/sum;
                Ps[(kq*4+r)*72 + lm     ] = f2bf(e0*inv);
                Ps[(kq*4+r)*72 + lm + 16] = f2bf(e1*inv);
                Ps[(kq*4+r)*72 + lm + 32] = f2bf(e2*inv);
                Ps[(kq*4+r)*72 + lm + 48] = f2bf(e3*inv);
            }
            f32x4 of[2];
            #pragma unroll
            for (int jt = 0; jt < 2; ++jt) of[jt] = (f32x4){0.f,0.f,0.f,0.f};
            #pragma unroll
            for (int ks = 0; ks < 2; ++ks){
                bf16x8 ap = ldf(Ps + lm*72 + ks*32 + kq*8);
                #pragma unroll
                for (int jt = 0; jt < 2; ++jt)
                    of[jt] = MFMA(ap, vf[jt][ks], of[jt]);
            }
            #pragma unroll
            for (int jt = 0; jt < 2; ++jt)
                #pragma unroll
                for (int r = 0; r < 4; ++r)
                    sm[0 + (mt*16+kq*4+r)*136 + wl*32+jt*16+lm] = f2bf(of[jt][r]);
        }
        __syncthreads();
        // ---- out-proj (reads QO) + gate2 (reads H) ----
        f32x4 accO[4][2], accG[4][2];
        #pragma unroll
        for (int rt = 0; rt < 4; ++rt)
            #pragma unroll
            for (int jt = 0; jt < 2; ++jt){
                accO[rt][jt] = (f32x4){ob[jt],ob[jt],ob[jt],ob[jt]};
                accG[rt][jt] = (f32x4){gb[jt],gb[jt],gb[jt],gb[jt]};
            }
        #pragma unroll
        for (int rt = 0; rt < 4; ++rt)
            #pragma unroll
            for (int ks = 0; ks < 4; ++ks){
                bf16x8 ao = ldf(sm + 0    + (rt*16+lm)*136 + ks*32 + kq*8);
                bf16x8 ah = ldf(sm + 8704 + (rt*16+lm)*136 + ks*32 + kq*8);
                #pragma unroll
                for (int jt = 0; jt < 2; ++jt){
                    accO[rt][jt] = MFMA(ao, wOf[jt][ks], accO[rt][jt]);
                    accG[rt][jt] = MFMA(ah, wGf[jt][ks], accG[rt][jt]);
                }
            }
        // residual: h2 = h1 + s2*sigmoid(G)*O  (reads H)
        #pragma unroll
        for (int rt = 0; rt < 4; ++rt)
            #pragma unroll
            for (int jt = 0; jt < 2; ++jt){
                int col = wl*32 + jt*16 + lm;
                #pragma unroll
                for (int r = 0; r < 4; ++r){
                    int lrow = rt*16 + kq*4 + r;
                    float hv = bf2f(sm[8704 + lrow*136 + col]);
                    float g = 1.f/(1.f + expf(-accG[rt][jt][r]));
                    accO[rt][jt][r] = hv + s2*g*accO[rt][jt][r];
                }
            }
        __syncthreads();   // all H reads done; H region becomes h2 (bf16, stride 132)
        #pragma unroll
        for (int rt = 0; rt < 4; ++rt)
            #pragma unroll
            for (int jt = 0; jt < 2; ++jt){
                int col = wl*32 + jt*16 + lm;
                #pragma unroll
                for (int r = 0; r < 4; ++r)
                    sm[8704 + (rt*16+kq*4+r)*132 + col] = f2bf(accO[rt][jt][r]);
            }
        __syncthreads();
        // ---- RMS + mixture ----
        {
            int r = tt >> 2, q = tt & 3;
            size_t row = r0 + r;
            const u16* h2p = sm + 8704 + r*132 + q*32;
            float h2a[32], v0a[32], v1a[32];
            float ss0 = 0.f, ss1 = 0.f, ss2 = 0.f, q0 = 0.f, q1 = 0.f, q2 = 0.f;
            #pragma unroll
            for (int c4 = 0; c4 < 8; ++c4){
                uint2 hk = *(const uint2*)(h2p + c4*4);
                float4 a0 = *(const float4*)(hist0 + row*C_ + q*32 + c4*4);
                float4 a1 = *(const float4*)(hist1 + row*C_ + q*32 + c4*4);
                const u16* pu = (const u16*)&hk;
                const float* p0 = (const float*)&a0;
                const float* p1 = (const float*)&a1;
                #pragma unroll
                for (int e = 0; e < 4; ++e){
                    float bw = sLn[256 + q*32 + c4*4 + e];
                    float x2 = bf2f(pu[e]), x0 = p0[e], x1 = p1[e];
                    h2a[c4*4+e] = x2; v0a[c4*4+e] = x0; v1a[c4*4+e] = x1;
                    ss0 += x0*x0; ss1 += x1*x1; ss2 += x2*x2;
                    q0 += bw*x0; q1 += bw*x1; q2 += bw*x2;
                }
            }
            ss0 += __shfl_xor(ss0,1); ss0 += __shfl_xor(ss0,2);
            ss1 += __shfl_xor(ss1,1); ss1 += __shfl_xor(ss1,2);
            ss2 += __shfl_xor(ss2,1); ss2 += __shfl_xor(ss2,2);
            q0 += __shfl_xor(q0,1); q0 += __shfl_xor(q0,2);
            q1 += __shfl_xor(q1,1); q1 += __shfl_xor(q1,2);
            q2 += __shfl_xor(q2,1); q2 += __shfl_xor(q2,2);
            float i0 = rsqrtf(ss0*(1.f/128.f) + 1e-6f);
            float i1 = rsqrtf(ss1*(1.f/128.f) + 1e-6f);
            float i2 = rsqrtf(ss2*(1.f/128.f) + 1e-6f);
            float l0 = fminf(fmaxf(q0*i0, -30.f), 30.f);
            float l1 = fminf(fmaxf(q1*i1, -30.f), 30.f);
            float l2 = fminf(fmaxf(q2*i2, -30.f), 30.f);
            float mx = fmaxf(l0, fmaxf(l1, l2));
            float e0 = expf(l0-mx), e1 = expf(l1-mx), e2 = expf(l2-mx);
            float isum = 1.f/(e0+e1+e2);
            #pragma unroll
            for (int c4 = 0; c4 < 8; ++c4){
                float o[4];
                #pragma unroll
                for (int e = 0; e < 4; ++e){
                    int i = c4*4+e;
                    o[e] = (e0*v0a[i] + e1*v1a[i] + e2*h2a[i])*isum;
                }
                *(float4*)(outp + row*C_ + q*32 + c4*4) = *(float4*)o;
            }
        }
        __syncthreads();
    }
}

extern "C" void kernel_launch(void* const* d_in, const int* in_sizes, int n_in,
                              void* d_out, int out_size, void* d_ws, size_t ws_size,
                              hipStream_t stream){
    (void)in_sizes; (void)n_in; (void)out_size; (void)ws_size;
    const float* h     = (const float*)d_in[0];
    const float* hist0 = (const float*)d_in[1];
    const float* hist1 = (const float*)d_in[2];
    const float* dw_w  = (const float*)d_in[3];
    const float* pw_w  = (const float*)d_in[4];
    const float* gn_w  = (const float*)d_in[5];
    const float* gn_b  = (const float*)d_in[6];
    const float* gr1_s = (const float*)d_in[7];
    const float* gr1_gw= (const float*)d_in[8];
    const float* gr1_gb= (const float*)d_in[9];
    const float* gtok  = (const float*)d_in[10];
    const float* in_w  = (const float*)d_in[11];
    const float* in_b  = (const float*)d_in[12];
    const float* out_w = (const float*)d_in[13];
    const float* out_b = (const float*)d_in[14];
    const float* ln_w  = (const float*)d_in[15];
    const float* ln_b  = (const float*)d_in[16];
    const float* gr2_s = (const float*)d_in[17];
    const float* gr2_gw= (const float*)d_in[18];
    const float* gr2_gb= (const float*)d_in[19];
    const float* rms_w = (const float*)d_in[20];
    const float* blk_w = (const float*)d_in[21];
    float* out = (float*)d_out;

    u16* ybf  = (u16*)d_out;                        // B*N*C bf16
    u16* hb16 = (u16*)d_out + (size_t)B_*N_*C_;     // B*N*C bf16

    float* W = (float*)d_ws;
    size_t off = 0;
    float* gstats  = W + off; off += 128;
    float* gfin    = W + off; off += 128;
    float* qhT     = W + off; off += 3*128*64;
    float* o_mean  = W + off; off += 3*B_*M_*C_;
    float* tokens  = W + off; off += B_*M_*C_;
    float* t_in    = W + off; off += B_*M_*C_;
    float* qkv3    = W + off; off += B_*M_*384;
    float* o3      = W + off; off += B_*M_*C_;
    float* tokens2 = W + off; off += B_*M_*C_;
    u16* U = (u16*)(W + off);
    size_t uo = 0;
    u16* h1b = U + uo; uo += (size_t)B_*N_*C_;
    u16* wA  = U + uo; uo += 256*128;
    u16* wKV = U + uo; uo += 3*256*128;
    u16* wQ  = U + uo; uo += 128*128;
    u16* wO  = U + uo; uo += 128*128;
    u16* wG2 = U + uo; uo += 128*128;
    u16* khs = U + uo; uo += B_*4*64*32;
    u16* vhb = U + uo; uo += B_*64*128;

    hipMemsetAsync(gstats, 0, 128*sizeof(float), stream);
    hipMemsetAsync(o_mean, 0, 3*B_*M_*C_*sizeof(float), stream);
    k_wcvt<<<704, 256, 0, stream>>>(pw_w, gr1_gw, in_w, out_w, gr2_gw, wA, wKV, wQ, wO, wG2);
    k_conv3<<<1024, 256, 0, stream>>>(h, dw_w, ybf, hb16, gstats);
    k_gstats_fin<<<1, 64, 0, stream>>>(gstats, gfin);
    k_stageA<<<1024, 256, 0, stream>>>(ybf, hb16, gfin, gn_w, gn_b, gr1_gb, gr1_s, wA, h1b);
    k_qh_axes<<<96, 256, 0, stream>>>(gtok, in_w, in_b, qhT);
    k_axis_attn<0,64,2048><<<512, 256, 0, stream>>>(h1b, wKV, in_b, qhT, o_mean);
    k_axis_attn<1,64,2048><<<512, 256, 0, stream>>>(h1b, wKV, in_b, qhT, o_mean);
    k_axis_attn<2,32,4096><<<1024, 256, 0, stream>>>(h1b, wKV, in_b, qhT, o_mean);
    k_tokens<<<64, 256, 0, stream>>>(o_mean, out_w, out_b, tokens);
    k_ln<<<B_*M_, 128, 0, stream>>>(tokens, ln_w, ln_b, t_in);
    k_qkv3<<<192, 256, 0, stream>>>(t_in, in_w, in_b, qkv3);
    k_attn3<<<8, 64, 0, stream>>>(qkv3, o3);
    k_tokens2<<<64, 256, 0, stream>>>(o3, out_w, out_b, tokens2);
    k_kv4<<<128, 256, 0, stream>>>(tokens2, in_w, in_b, khs, vhb);
    k_globfinal<<<1024, 512, 0, stream>>>(h1b, wQ, wO, wG2, khs, vhb, in_b, out_b,
                                          gr2_gb, gr2_s, ln_w, ln_b, hist0, hist1, rms_w, blk_w, out);
}

// Round 10
// 1112.232 us; speedup vs baseline: 1.0140x; 1.0140x over previous
//
#include <hip/hip_runtime.h>
#include <hip/hip_bf16.h>

#define B_ 2
#define C_ 128
#define HX_ 64
#define HY_ 64
#define HZ_ 32
#define N_ 131072
#define M_ 64
#define G_ 32
#define SCALE_ 0.17677669529663687f  // 1/sqrt(32)

typedef unsigned short u16;
typedef __bf16 bf16x8 __attribute__((ext_vector_type(8)));
typedef float f32x4 __attribute__((ext_vector_type(4)));

#define MFMA(a, b, c) __builtin_amdgcn_mfma_f32_16x16x32_bf16(a, b, c, 0, 0, 0)

__device__ __forceinline__ float bf2f(u16 u){
    return __uint_as_float(((unsigned int)u) << 16);
}
__device__ __forceinline__ u16 f2bf(float f){
    unsigned int u = __float_as_uint(f);
    unsigned int r = (u + 0x7FFFu + ((u >> 16) & 1u)) >> 16;
    return (u16)r;
}
__device__ __forceinline__ bf16x8 ldf(const u16* p){
    return __builtin_bit_cast(bf16x8, *reinterpret_cast<const uint4*>(p));
}
__device__ __forceinline__ float wred_sum(float v){
    for (int o = 32; o; o >>= 1) v += __shfl_xor(v, o);
    return v;
}

// ---------------- weight conversion to bf16 ----------------
__global__ __launch_bounds__(256) void k_wcvt(const float* __restrict__ pw, const float* __restrict__ g1w,
        const float* __restrict__ in_w, const float* __restrict__ out_w, const float* __restrict__ g2w,
        u16* __restrict__ wA, u16* __restrict__ wKV, u16* __restrict__ wQ, u16* __restrict__ wO, u16* __restrict__ wG2){
    int idx = blockIdx.x*256 + threadIdx.x;
    if (idx < 32768){
        int j = idx >> 7, k = idx & 127;
        wA[idx] = f2bf(j < 128 ? pw[j*128 + k] : g1w[(j-128)*128 + k]);
    } else if (idx < 131072){
        int r = idx - 32768;
        int a = r >> 15, jk = r & 32767;
        int j = jk >> 7, k = jk & 127;
        wKV[r] = f2bf(in_w[((size_t)a*384 + 128 + j)*128 + k]);
    } else if (idx < 147456){
        int r = idx - 131072;
        wQ[r] = f2bf(in_w[4*384*128 + r]);
    } else if (idx < 163840){
        int r = idx - 147456;
        wO[r] = f2bf(out_w[4*128*128 + r]);
    } else if (idx < 180224){
        int r = idx - 163840;
        wG2[r] = f2bf(g2w[r]);
    }
}

// ---------------- depthwise conv3d, float4-vectorized z-sliding + group stats ----------------
__global__ __launch_bounds__(256, 2) void k_conv3(const float* __restrict__ h,
        const float* __restrict__ dw_w, u16* __restrict__ ybf, u16* __restrict__ hb16,
        float* __restrict__ gstats){
    int t = threadIdx.x;
    int lane = t & 31;            // channel quad == GN group
    int c4 = lane << 2;
    int xg = t >> 5;              // 0..7
    int bi = blockIdx.x;          // [0, B*64*8)
    int b = bi >> 9;
    int y = (bi >> 3) & 63;
    int x = ((bi & 7) << 3) | xg;
    const float* hb = h + (size_t)b*N_*C_;
    u16* yb = ybf + (size_t)b*N_*C_;
    u16* hbb = hb16 + (size_t)b*N_*C_;
    f32x4 wv[27];
    int off[9];
    #pragma unroll
    for (int dxi = 0; dxi < 3; ++dxi){
        #pragma unroll
        for (int dyi = 0; dyi < 3; ++dyi){
            int xr = x + dxi - 1, yr = y + dyi - 1;
            float m = (xr >= 0 && xr < HX_ && yr >= 0 && yr < HY_) ? 1.f : 0.f;
            int xx = min(max(xr, 0), HX_-1);
            int yy = min(max(yr, 0), HY_-1);
            off[dxi*3+dyi] = (yy*64 + xx)*128 + c4;
            #pragma unroll
            for (int dzi = 0; dzi < 3; ++dzi){
                int k = (dxi*3+dyi)*3+dzi;
                int wk = dxi*9 + dyi*3 + dzi;
                f32x4 wq;
                #pragma unroll
                for (int e = 0; e < 4; ++e) wq[e] = dw_w[(c4+e)*27 + wk] * m;
                wv[k] = wq;
            }
        }
    }
    f32x4 accA = {0,0,0,0}, accB = {0,0,0,0}, accC = {0,0,0,0};
    f32x4 sum4 = {0,0,0,0}, ss4 = {0,0,0,0};
    #pragma unroll 2
    for (int zp = 0; zp < 32; ++zp){
        size_t zb = (size_t)zp*524288;
        f32x4 v[9];
        #pragma unroll
        for (int j = 0; j < 9; ++j) v[j] = *(const f32x4*)(hb + zb + off[j]);
        {
            unsigned int p0 = (unsigned int)f2bf(v[4][0]) | ((unsigned int)f2bf(v[4][1]) << 16);
            unsigned int p1 = (unsigned int)f2bf(v[4][2]) | ((unsigned int)f2bf(v[4][3]) << 16);
            uint2 pk = {p0, p1};
            *(uint2*)(hbb + zb + off[4]) = pk;
        }
        f32x4 s0 = {0,0,0,0}, s1 = {0,0,0,0}, s2 = {0,0,0,0};
        #pragma unroll
        for (int j = 0; j < 9; ++j){
            s0 += v[j]*wv[j*3+0];
            s1 += v[j]*wv[j*3+1];
            s2 += v[j]*wv[j*3+2];
        }
        accA += s2; accB += s1; accC += s0;
        if (zp >= 1){
            f32x4 yv = accA;
            sum4 += yv; ss4 += yv*yv;
            unsigned int p0 = (unsigned int)f2bf(yv[0]) | ((unsigned int)f2bf(yv[1]) << 16);
            unsigned int p1 = (unsigned int)f2bf(yv[2]) | ((unsigned int)f2bf(yv[3]) << 16);
            uint2 pk = {p0, p1};
            *(uint2*)(yb + (size_t)(zp-1)*524288 + off[4]) = pk;
        }
        accA = accB; accB = accC; accC = (f32x4){0,0,0,0};
    }
    {
        f32x4 yv = accA;   // out(31)
        sum4 += yv; ss4 += yv*yv;
        unsigned int p0 = (unsigned int)f2bf(yv[0]) | ((unsigned int)f2bf(yv[1]) << 16);
        unsigned int p1 = (unsigned int)f2bf(yv[2]) | ((unsigned int)f2bf(yv[3]) << 16);
        uint2 pk = {p0, p1};
        *(uint2*)(yb + (size_t)31*524288 + off[4]) = pk;
    }
    float sum = sum4[0]+sum4[1]+sum4[2]+sum4[3];
    float ss  = ss4[0]+ss4[1]+ss4[2]+ss4[3];
    sum += __shfl_xor(sum, 32);
    ss  += __shfl_xor(ss, 32);
    if ((t & 32) == 0){
        atomicAdd(&gstats[(b*G_ + lane)*2 + 0], sum);
        atomicAdd(&gstats[(b*G_ + lane)*2 + 1], ss);
    }
}

__global__ void k_gstats_fin(const float* __restrict__ gstats, float* __restrict__ gfin){
    int t = threadIdx.x;
    if (t < B_*G_){
        const float cnt = 4.f * (float)N_;
        float mean = gstats[t*2] / cnt;
        float var  = gstats[t*2+1] / cnt - mean*mean;
        gfin[t*2]   = mean;
        gfin[t*2+1] = rsqrtf(var + 1e-5f);
    }
}

// ---------------- stage A: GN+GELU (fused) + pointwise + gate1 via MFMA ----------------
__global__ __launch_bounds__(256) void k_stageA(const u16* __restrict__ ybf, const u16* __restrict__ hb16,
        const float* __restrict__ gfin, const float* __restrict__ gn_w, const float* __restrict__ gn_b,
        const float* __restrict__ g1b, const float* __restrict__ s1p,
        const u16* __restrict__ wA, u16* __restrict__ h1b){
    __shared__ __align__(16) u16 sU[64*136];
    __shared__ __align__(16) u16 sH[64*136];
    __shared__ float sPar[384];
    int t = threadIdx.x;
    int w = t >> 6, l = t & 63, lm = l & 15, kq = l >> 4;
    if (t < 128){ sPar[t] = gn_w[t]; sPar[128+t] = gn_b[t]; sPar[256+t] = gfin[t]; }
    bf16x8 wUf[2][4], wGf[2][4];
    float gbias[2];
    #pragma unroll
    for (int jt = 0; jt < 2; ++jt){
        int j = w*32 + jt*16 + lm;
        gbias[jt] = g1b[j];
        #pragma unroll
        for (int ks = 0; ks < 4; ++ks){
            wUf[jt][ks] = ldf(wA + (size_t)j*128 + ks*32 + kq*8);
            wGf[jt][ks] = ldf(wA + (size_t)(128+j)*128 + ks*32 + kq*8);
        }
    }
    float s1 = s1p[0];
    __syncthreads();
    for (int it = 0; it < 4; ++it){
        int tile = blockIdx.x + it*1024;
        size_t r0 = (size_t)tile*64;
        int bsel = (tile >= 2048) ? 1 : 0;
        for (int pass = 0; pass < 4; ++pass){
            int cid = pass*256 + t;
            int row = cid >> 4, col8 = (cid & 15)*8;
            size_t gi = (r0 + row)*C_ + col8;
            uint4 yraw = *(const uint4*)(ybf + gi);
            uint4 hraw = *(const uint4*)(hb16 + gi);
            const u16* yp = (const u16*)&yraw;
            unsigned int pu[4];
            #pragma unroll
            for (int p2 = 0; p2 < 4; ++p2){
                u16 r2[2];
                #pragma unroll
                for (int e2 = 0; e2 < 2; ++e2){
                    int e = p2*2 + e2;
                    int ch = col8 + e;
                    int g = ch >> 2;
                    float mean = sPar[256 + (bsel*32+g)*2];
                    float inv  = sPar[256 + (bsel*32+g)*2 + 1];
                    float v = (bf2f(yp[e]) - mean)*inv*sPar[ch] + sPar[128+ch];
                    float u = 0.5f*v*(1.f + erff(v*0.70710678118654752f));
                    r2[e2] = f2bf(u);
                }
                pu[p2] = (unsigned int)r2[0] | ((unsigned int)r2[1] << 16);
            }
            *(uint4*)(sU + row*136 + col8) = *(uint4*)pu;
            *(uint4*)(sH + row*136 + col8) = hraw;
        }
        __syncthreads();
        f32x4 accU[4][2], accG[4][2];
        #pragma unroll
        for (int rt = 0; rt < 4; ++rt)
            #pragma unroll
            for (int jt = 0; jt < 2; ++jt){
                accU[rt][jt] = (f32x4){0.f,0.f,0.f,0.f};
                accG[rt][jt] = (f32x4){gbias[jt],gbias[jt],gbias[jt],gbias[jt]};
            }
        #pragma unroll
        for (int rt = 0; rt < 4; ++rt)
            #pragma unroll
            for (int ks = 0; ks < 4; ++ks){
                bf16x8 aU = ldf(sU + (rt*16+lm)*136 + ks*32 + kq*8);
                bf16x8 aH = ldf(sH + (rt*16+lm)*136 + ks*32 + kq*8);
                #pragma unroll
                for (int jt = 0; jt < 2; ++jt){
                    accU[rt][jt] = MFMA(aU, wUf[jt][ks], accU[rt][jt]);
                    accG[rt][jt] = MFMA(aH, wGf[jt][ks], accG[rt][jt]);
                }
            }
        #pragma unroll
        for (int rt = 0; rt < 4; ++rt)
            #pragma unroll
            for (int jt = 0; jt < 2; ++jt){
                int col = w*32 + jt*16 + lm;
                #pragma unroll
                for (int r = 0; r < 4; ++r){
                    int lrow = rt*16 + kq*4 + r;
                    float g = 1.f/(1.f + expf(-accG[rt][jt][r]));
                    float hv = bf2f(sH[lrow*136 + col]);
                    float h1v = hv + s1*g*accU[rt][jt][r];
                    h1b[(r0 + lrow)*C_ + col] = f2bf(h1v);
                }
            }
        __syncthreads();
    }
}

// ---------------- axis attention Q projection (tiny, fp32) ----------------
__global__ __launch_bounds__(256) void k_qh_axes(const float* __restrict__ gtok,
        const float* __restrict__ in_w, const float* __restrict__ in_b, float* __restrict__ qhT){
    int idx = blockIdx.x*256 + threadIdx.x;   // [0, 3*128*64)
    int m = idx & 63;
    int hd = (idx >> 6) & 127;
    int a = idx >> 13;
    float acc = in_b[a*384 + hd];
    const float* w = in_w + ((size_t)a*384 + hd)*C_;
    const float* q = gtok + (size_t)m*C_;
    for (int c = 0; c < C_; ++c) acc += q[c]*w[c];
    qhT[idx] = acc;
}

// ---------------- axis attentions: full-MFMA (kvproj + QK^T + PV) ----------------
template<int AXIS, int L, int S>
__global__ __launch_bounds__(256, 2) void k_axis_attn(const u16* __restrict__ h1b,
        const u16* __restrict__ wKVb, const float* __restrict__ in_b,
        const float* __restrict__ qhT, float* __restrict__ o_mean){
    constexpr int SLICES = 8;
    constexpr int PARTS = S / SLICES;
    constexpr int PSROW = L + 8;
    constexpr int PSZ = 64 * PSROW;
    constexpr int NT = L / 16;
    constexpr int KS = L / 32;
    __shared__ __align__(16) u16 sm[6*PSZ];
    int t = threadIdx.x;
    int w = t >> 6, l = t & 63, lm = l & 15, kq = l >> 4;
    int b = blockIdx.x / PARTS;
    int part = blockIdx.x % PARTS;
    u16* rows = sm;
    u16* kv   = sm + 2*PSZ;
    u16* vT   = sm + 4*PSZ;
    u16* Ps   = sm + w*PSZ;
    bf16x8 wf[4][4];
    float bias[4];
    #pragma unroll
    for (int jt = 0; jt < 4; ++jt){
        int j = w*64 + jt*16 + lm;
        bias[jt] = in_b[AXIS*384 + 128 + j];
        #pragma unroll
        for (int ks = 0; ks < 4; ++ks)
            wf[jt][ks] = ldf(wKVb + ((size_t)AXIS*256 + j)*128 + ks*32 + kq*8);
    }
    bf16x8 qf[4];
    #pragma unroll
    for (int mt = 0; mt < 4; ++mt){
        union { u16 u[8]; bf16x8 v; } tmp;
        #pragma unroll
        for (int e = 0; e < 8; ++e)
            tmp.u[e] = f2bf(qhT[(AXIS*C_ + w*32 + kq*8 + e)*64 + mt*16 + lm] * SCALE_);
        qf[mt] = tmp.v;
    }
    f32x4 oacc[4][2];
    #pragma unroll
    for (int mt = 0; mt < 4; ++mt)
        #pragma unroll
        for (int dt = 0; dt < 2; ++dt)
            oacc[mt][dt] = (f32x4){0.f,0.f,0.f,0.f};
    const u16* hb = h1b + (size_t)b*N_*C_;
    for (int si = 0; si < SLICES; ++si){
        int s = part*SLICES + si;
        for (int ci = t; ci < L*16; ci += 256){
            int p = ci >> 4, c8 = (ci & 15)*8;
            int n;
            if (AXIS == 0){ int yy = s >> 5, zz = s & 31; n = zz*4096 + yy*64 + p; }
            else if (AXIS == 1){ int xx = s >> 5, zz = s & 31; n = zz*4096 + p*64 + xx; }
            else { int xx = s >> 6, yy = s & 63; n = p*4096 + yy*64 + xx; }
            *(uint4*)(rows + p*136 + c8) = *(const uint4*)(hb + (size_t)n*C_ + c8);
        }
        __syncthreads();
        #pragma unroll
        for (int rt = 0; rt < NT; ++rt){
            f32x4 acc[4];
            #pragma unroll
            for (int jt = 0; jt < 4; ++jt) acc[jt] = (f32x4){bias[jt],bias[jt],bias[jt],bias[jt]};
            #pragma unroll
            for (int ks = 0; ks < 4; ++ks){
                bf16x8 a = ldf(rows + (rt*16+lm)*136 + ks*32 + kq*8);
                #pragma unroll
                for (int jt = 0; jt < 4; ++jt) acc[jt] = MFMA(a, wf[jt][ks], acc[jt]);
            }
            #pragma unroll
            for (int jt = 0; jt < 4; ++jt){
                int j = w*64 + jt*16 + lm;
                #pragma unroll
                for (int r = 0; r < 4; ++r){
                    int key = rt*16 + kq*4 + r;
                    if (w < 2) kv[key*136 + j] = f2bf(acc[jt][r]);
                    else       vT[(j-128)*PSROW + key] = f2bf(acc[jt][r]);
                }
            }
        }
        __syncthreads();
        f32x4 lacc[4][NT];
        #pragma unroll
        for (int mt = 0; mt < 4; ++mt)
            #pragma unroll
            for (int nt = 0; nt < NT; ++nt) lacc[mt][nt] = (f32x4){0.f,0.f,0.f,0.f};
        #pragma unroll
        for (int nt = 0; nt < NT; ++nt){
            bf16x8 kf = ldf(kv + (nt*16+lm)*136 + w*32 + kq*8);
            #pragma unroll
            for (int mt = 0; mt < 4; ++mt) lacc[mt][nt] = MFMA(qf[mt], kf, lacc[mt][nt]);
        }
        __syncthreads();
        #pragma unroll
        for (int mt = 0; mt < 4; ++mt){
            #pragma unroll
            for (int r = 0; r < 4; ++r){
                float mx = lacc[mt][0][r];
                #pragma unroll
                for (int nt = 1; nt < NT; ++nt) mx = fmaxf(mx, lacc[mt][nt][r]);
                mx = fmaxf(mx, __shfl_xor(mx,1));
                mx = fmaxf(mx, __shfl_xor(mx,2));
                mx = fmaxf(mx, __shfl_xor(mx,4));
                mx = fmaxf(mx, __shfl_xor(mx,8));
                float ev[NT]; float sum = 0.f;
                #pragma unroll
                for (int nt = 0; nt < NT; ++nt){ ev[nt] = expf(lacc[mt][nt][r] - mx); sum += ev[nt]; }
                sum += __shfl_xor(sum,1);
                sum += __shfl_xor(sum,2);
                sum += __shfl_xor(sum,4);
                sum += __shfl_xor(sum,8);
                float inv = 1.f/sum;
                #pragma unroll
                for (int nt = 0; nt < NT; ++nt)
                    Ps[(mt*16 + kq*4 + r)*PSROW + nt*16 + lm] = f2bf(ev[nt]*inv);
            }
        }
        #pragma unroll
        for (int ks = 0; ks < KS; ++ks){
            bf16x8 vb[2];
            #pragma unroll
            for (int dt = 0; dt < 2; ++dt)
                vb[dt] = ldf(vT + (w*32 + dt*16 + lm)*PSROW + ks*32 + kq*8);
            #pragma unroll
            for (int mt = 0; mt < 4; ++mt){
                bf16x8 pa = ldf(Ps + (mt*16+lm)*PSROW + ks*32 + kq*8);
                #pragma unroll
                for (int dt = 0; dt < 2; ++dt)
                    oacc[mt][dt] = MFMA(pa, vb[dt], oacc[mt][dt]);
            }
        }
        __syncthreads();
    }
    const float invS = 1.f / (float)S;
    float* om = o_mean + (size_t)(AXIS*B_ + b)*M_*C_;
    #pragma unroll
    for (int mt = 0; mt < 4; ++mt)
        #pragma unroll
        for (int dt = 0; dt < 2; ++dt)
            #pragma unroll
            for (int r = 0; r < 4; ++r){
                int m = mt*16 + kq*4 + r;
                int d = dt*16 + lm;
                atomicAdd(&om[m*C_ + w*32 + d], oacc[mt][dt][r]*invS);
            }
}

// ---------------- token chain (small, fp32) ----------------
__global__ __launch_bounds__(256) void k_tokens(const float* __restrict__ o_mean,
        const float* __restrict__ out_w, const float* __restrict__ out_b, float* __restrict__ tokens){
    int idx = blockIdx.x*256 + threadIdx.x;  // [0, B*M*C)
    int c = idx & 127;
    int m = (idx >> 7) & 63;
    int b = idx >> 13;
    float acc = 0.f;
    for (int a = 0; a < 3; ++a){
        const float* om = o_mean + ((size_t)(a*B_ + b)*M_ + m)*C_;
        const float* w = out_w + ((size_t)a*C_ + c)*C_;
        float s = out_b[a*C_ + c];
        for (int k = 0; k < C_; ++k) s += om[k]*w[k];
        acc += s;
    }
    tokens[idx] = acc;
}

__global__ __launch_bounds__(128) void k_ln(const float* __restrict__ in,
        const float* __restrict__ w, const float* __restrict__ b, float* __restrict__ out){
    int r = blockIdx.x;
    int c = threadIdx.x;
    float v = in[(size_t)r*C_ + c];
    __shared__ float red[4];
    float s = wred_sum(v), ss = wred_sum(v*v);
    int wv = c >> 6;
    if ((c & 63) == 0){ red[wv*2] = s; red[wv*2+1] = ss; }
    __syncthreads();
    float S = red[0] + red[2], SS = red[1] + red[3];
    float mean = S / 128.f;
    float var = SS / 128.f - mean*mean;
    out[(size_t)r*C_ + c] = (v - mean) * rsqrtf(var + 1e-5f) * w[c] + b[c];
}

__global__ __launch_bounds__(256) void k_qkv3(const float* __restrict__ t_in,
        const float* __restrict__ in_w, const float* __restrict__ in_b, float* __restrict__ qkv3){
    int idx = blockIdx.x*256 + threadIdx.x;  // [0, B*M*384)
    int j = idx % 384;
    int m = (idx / 384) & 63;
    int b = idx / (384*64);
    const float* x = t_in + ((size_t)b*64 + m)*C_;
    const float* w = in_w + ((size_t)3*384 + j)*C_;
    float acc = in_b[3*384 + j];
    for (int c = 0; c < C_; ++c) acc += x[c]*w[c];
    qkv3[idx] = acc;
}

__global__ __launch_bounds__(64) void k_attn3(const float* __restrict__ qkv3, float* __restrict__ o3){
    int b = blockIdx.x >> 2, hh = blockIdx.x & 3;
    int m = threadIdx.x;
    const float* base = qkv3 + (size_t)b*64*384;
    float q[32];
    #pragma unroll
    for (int d = 0; d < 32; ++d) q[d] = base[m*384 + hh*32 + d];
    float lg[64]; float mx = -1e30f;
    for (int mk = 0; mk < 64; ++mk){
        float acc = 0.f;
        #pragma unroll
        for (int d = 0; d < 32; ++d) acc += q[d] * base[mk*384 + 128 + hh*32 + d];
        acc *= SCALE_;
        lg[mk] = acc; mx = fmaxf(mx, acc);
    }
    float sum = 0.f;
    #pragma unroll
    for (int mk = 0; mk < 64; ++mk){ float e = expf(lg[mk]-mx); lg[mk] = e; sum += e; }
    float inv = 1.f/sum;
    float o[32];
    #pragma unroll
    for (int d = 0; d < 32; ++d) o[d] = 0.f;
    for (int mk = 0; mk < 64; ++mk){
        float al = lg[mk]*inv;
        #pragma unroll
        for (int d = 0; d < 32; ++d) o[d] += al * base[mk*384 + 256 + hh*32 + d];
    }
    #pragma unroll
    for (int d = 0; d < 32; ++d) o3[((size_t)b*64 + m)*C_ + hh*32 + d] = o[d];
}

__global__ __launch_bounds__(256) void k_tokens2(const float* __restrict__ o3,
        const float* __restrict__ out_w, const float* __restrict__ out_b, float* __restrict__ tokens2){
    int idx = blockIdx.x*256 + threadIdx.x;
    int c = idx & 127;
    int m = (idx >> 7) & 63;
    int b = idx >> 13;
    const float* x = o3 + ((size_t)b*64 + m)*C_;
    const float* w = out_w + ((size_t)3*C_ + c)*C_;
    float acc = out_b[3*C_ + c];
    for (int k = 0; k < C_; ++k) acc += x[k]*w[k];
    tokens2[idx] = acc;
}

// kh: [b][h][key][32d] bf16, pre-scaled by SCALE_.  vh: [b][key][128] bf16.
__global__ __launch_bounds__(256) void k_kv4(const float* __restrict__ tokens2,
        const float* __restrict__ in_w, const float* __restrict__ in_b,
        u16* __restrict__ khs, u16* __restrict__ vhb){
    int idx = blockIdx.x*256 + threadIdx.x;   // [0, B*16384)
    int b = idx >> 14;
    int r = idx & 16383;
    if (r < 8192){
        int hh = r >> 11, key = (r >> 5) & 63, d = r & 31;
        int hd = hh*32 + d;
        const float* x = tokens2 + ((size_t)b*64 + key)*C_;
        const float* w = in_w + ((size_t)4*384 + 128 + hd)*C_;
        float acc = in_b[4*384 + 128 + hd];
        for (int c = 0; c < C_; ++c) acc += x[c]*w[c];
        khs[(size_t)b*8192 + r] = f2bf(acc * SCALE_);
    } else {
        int rr = r - 8192;
        int key = rr >> 7, c = rr & 127;
        const float* x = tokens2 + ((size_t)b*64 + key)*C_;
        const float* w = in_w + ((size_t)4*384 + 256 + c)*C_;
        float acc = in_b[4*384 + 256 + c];
        for (int k = 0; k < 128; ++k) acc += x[k]*w[k];
        vhb[(size_t)b*8192 + rr] = f2bf(acc);
    }
}

// ---------------- fused: LN -> Qproj -> attn -> outproj -> gate2 -> RMS mixture ----------------
// 512 threads = 2 independent 64-row tiles (waves 0-3 tile 0, waves 4-7 tile 1).
// __launch_bounds__(512, 1): 1 block/CU (8 waves, 2/SIMD) -> VGPR cap 256, no spills.
// Per-tile LDS (u16, 22016): X/QO [0,8704) ; H then h2(bf16, stride 132) [8704,17408) ; P [17408,22016)
__global__ __launch_bounds__(512, 1) void k_globfinal(const u16* __restrict__ h1b,
        const u16* __restrict__ wQb, const u16* __restrict__ wOb, const u16* __restrict__ wG2b,
        const u16* __restrict__ khs, const u16* __restrict__ vhb,
        const float* __restrict__ in_b, const float* __restrict__ out_b,
        const float* __restrict__ g2b, const float* __restrict__ s2p,
        const float* __restrict__ ln_w, const float* __restrict__ ln_b,
        const float* __restrict__ hist0, const float* __restrict__ hist1,
        const float* __restrict__ rms_w, const float* __restrict__ blk_w,
        float* __restrict__ outp){
    __shared__ __align__(16) u16 smb[44032];
    __shared__ float sLn[384];
    int t = threadIdx.x;
    int w8 = t >> 6;              // 0..7
    int ti = w8 >> 2;             // tile within block
    int wl = w8 & 3;              // wave within tile (= head)
    int l = t & 63, lm = l & 15, kq = l >> 4;
    int tt = t & 255;             // thread within tile
    u16* sm = smb + ti*22016;
    if (t < 128){ sLn[t] = ln_w[128+t]; sLn[128+t] = ln_b[128+t]; sLn[256+t] = blk_w[t]*rms_w[t]; }
    int b = blockIdx.x >> 9;
    bf16x8 wQf[2][4], wOf[2][4], wGf[2][4], khf[4], vf[2][2];
    float qb[2], ob[2], gb[2];
    #pragma unroll
    for (int jt = 0; jt < 2; ++jt){
        int j = wl*32 + jt*16 + lm;
        qb[jt] = in_b[4*384 + j];
        ob[jt] = out_b[4*128 + j];
        gb[jt] = g2b[j];
        #pragma unroll
        for (int ks = 0; ks < 4; ++ks){
            wQf[jt][ks] = ldf(wQb + (size_t)j*128 + ks*32 + kq*8);
            wOf[jt][ks] = ldf(wOb + (size_t)j*128 + ks*32 + kq*8);
            wGf[jt][ks] = ldf(wG2b + (size_t)j*128 + ks*32 + kq*8);
        }
    }
    #pragma unroll
    for (int jt = 0; jt < 4; ++jt)
        khf[jt] = ldf(khs + ((size_t)(b*4 + wl)*64 + jt*16 + lm)*32 + kq*8);
    #pragma unroll
    for (int jt = 0; jt < 2; ++jt)
        #pragma unroll
        for (int ks = 0; ks < 2; ++ks){
            union { u16 u[8]; bf16x8 v; } tmp;
            #pragma unroll
            for (int e = 0; e < 8; ++e){
                int key = ks*32 + kq*8 + e;
                tmp.u[e] = vhb[(size_t)(b*64 + key)*128 + wl*32 + jt*16 + lm];
            }
            vf[jt][ks] = tmp.v;
        }
    float s2 = s2p[0];
    __syncthreads();

    for (int it = 0; it < 2; ++it){
        int pair = (blockIdx.x & 511) + it*512;
        int tile = pair*2 + ti;
        size_t r0 = (size_t)b*N_ + (size_t)tile*64;
        // ---- stage h1 (raw -> H) + LN (-> X) ----
        {
            int r = tt >> 2, q = tt & 3;
            const u16* src = h1b + (r0 + r)*C_ + q*32;
            uint4 raw[4];
            float v[32];
            float s = 0.f, ss = 0.f;
            #pragma unroll
            for (int c4 = 0; c4 < 4; ++c4){
                raw[c4] = *(const uint4*)(src + c4*8);
                const u16* pu = (const u16*)&raw[c4];
                #pragma unroll
                for (int e = 0; e < 8; ++e){ float x = bf2f(pu[e]); v[c4*8+e] = x; s += x; ss += x*x; }
            }
            s += __shfl_xor(s,1); s += __shfl_xor(s,2);
            ss += __shfl_xor(ss,1); ss += __shfl_xor(ss,2);
            float mean = s*(1.f/128.f);
            float inv = rsqrtf(ss*(1.f/128.f) - mean*mean + 1e-5f);
            #pragma unroll
            for (int c4 = 0; c4 < 4; ++c4){
                unsigned int o[4];
                #pragma unroll
                for (int p2 = 0; p2 < 4; ++p2){
                    int c = q*32 + c4*8 + p2*2;
                    u16 a0 = f2bf((v[c4*8+p2*2]   - mean)*inv*sLn[c]   + sLn[128+c]);
                    u16 a1 = f2bf((v[c4*8+p2*2+1] - mean)*inv*sLn[c+1] + sLn[128+c+1]);
                    o[p2] = (unsigned int)a0 | ((unsigned int)a1 << 16);
                }
                *(uint4*)(sm + 0    + r*136 + q*32 + c4*8) = *(uint4*)o;
                *(uint4*)(sm + 8704 + r*136 + q*32 + c4*8) = raw[c4];
            }
        }
        __syncthreads();
        // ---- q projection (reads X) ----
        f32x4 accQ[4][2];
        #pragma unroll
        for (int rt = 0; rt < 4; ++rt)
            #pragma unroll
            for (int jt = 0; jt < 2; ++jt)
                accQ[rt][jt] = (f32x4){qb[jt],qb[jt],qb[jt],qb[jt]};
        #pragma unroll
        for (int rt = 0; rt < 4; ++rt)
            #pragma unroll
            for (int ks = 0; ks < 4; ++ks){
                bf16x8 a = ldf(sm + 0 + (rt*16+lm)*136 + ks*32 + kq*8);
                #pragma unroll
                for (int jt = 0; jt < 2; ++jt)
                    accQ[rt][jt] = MFMA(a, wQf[jt][ks], accQ[rt][jt]);
            }
        __syncthreads();   // all X reads done; X region becomes QO
        #pragma unroll
        for (int rt = 0; rt < 4; ++rt)
            #pragma unroll
            for (int jt = 0; jt < 2; ++jt)
                #pragma unroll
                for (int r = 0; r < 4; ++r)
                    sm[0 + (rt*16+kq*4+r)*136 + wl*32+jt*16+lm] = f2bf(accQ[rt][jt][r]);
        // ---- logits + softmax + PV (wave = head; QO cols wave-private) ----
        u16* Ps = sm + 17408 + wl*1152;
        #pragma unroll
        for (int mt = 0; mt < 4; ++mt){
            bf16x8 aq = ldf(sm + 0 + (mt*16+lm)*136 + wl*32 + kq*8);
            f32x4 lacc[4];
            #pragma unroll
            for (int jt = 0; jt < 4; ++jt) lacc[jt] = (f32x4){0.f,0.f,0.f,0.f};
            #pragma unroll
            for (int jt = 0; jt < 4; ++jt) lacc[jt] = MFMA(aq, khf[jt], lacc[jt]);
            #pragma unroll
            for (int r = 0; r < 4; ++r){
                float v0 = lacc[0][r], v1 = lacc[1][r], v2 = lacc[2][r], v3 = lacc[3][r];
                float mx = fmaxf(fmaxf(v0,v1), fmaxf(v2,v3));
                mx = fmaxf(mx, __shfl_xor(mx,1));
                mx = fmaxf(mx, __shfl_xor(mx,2));
                mx = fmaxf(mx, __shfl_xor(mx,4));
                mx = fmaxf(mx, __shfl_xor(mx,8));
                float e0 = expf(v0-mx), e1 = expf(v1-mx), e2 = expf(v2-mx), e3 = expf(v3-mx);
                float sum = e0+e1+e2+e3;
                sum += __shfl_xor(sum,1);
                sum += __shfl_xor(sum,2);
                sum += __shfl_xor(sum,4);
                sum += __shfl_xor(sum,8);
                float inv = 1.f/sum;
                Ps[(kq*4+r)*72 + lm     ] = f2bf(e0*inv);
                Ps[(kq*4+r)*72 + lm + 16] = f2bf(e1*inv);
                Ps[(kq*4+r)*72 + lm + 32] = f2bf(e2*inv);
                Ps[(kq*4+r)*72 + lm + 48] = f2bf(e3*inv);
            }
            f32x4 of[2];
            #pragma unroll
            for (int jt = 0; jt < 2; ++jt) of[jt] = (f32x4){0.f,0.f,0.f,0.f};
            #pragma unroll
            for (int ks = 0; ks < 2; ++ks){
                bf16x8 ap = ldf(Ps + lm*72 + ks*32 + kq*8);
                #pragma unroll
                for (int jt = 0; jt < 2; ++jt)
                    of[jt] = MFMA(ap, vf[jt][ks], of[jt]);
            }
            #pragma unroll
            for (int jt = 0; jt < 2; ++jt)
                #pragma unroll
                for (int r = 0; r < 4; ++r)
                    sm[0 + (mt*16+kq*4+r)*136 + wl*32+jt*16+lm] = f2bf(of[jt][r]);
        }
        __syncthreads();
        // ---- out-proj (reads QO) + gate2 (reads H) ----
        f32x4 accO[4][2], accG[4][2];
        #pragma unroll
        for (int rt = 0; rt < 4; ++rt)
            #pragma unroll
            for (int jt = 0; jt < 2; ++jt){
                accO[rt][jt] = (f32x4){ob[jt],ob[jt],ob[jt],ob[jt]};
                accG[rt][jt] = (f32x4){gb[jt],gb[jt],gb[jt],gb[jt]};
            }
        #pragma unroll
        for (int rt = 0; rt < 4; ++rt)
            #pragma unroll
            for (int ks = 0; ks < 4; ++ks){
                bf16x8 ao = ldf(sm + 0    + (rt*16+lm)*136 + ks*32 + kq*8);
                bf16x8 ah = ldf(sm + 8704 + (rt*16+lm)*136 + ks*32 + kq*8);
                #pragma unroll
                for (int jt = 0; jt < 2; ++jt){
                    accO[rt][jt] = MFMA(ao, wOf[jt][ks], accO[rt][jt]);
                    accG[rt][jt] = MFMA(ah, wGf[jt][ks], accG[rt][jt]);
                }
            }
        // residual: h2 = h1 + s2*sigmoid(G)*O  (reads H)
        #pragma unroll
        for (int rt = 0; rt < 4; ++rt)
            #pragma unroll
            for (int jt = 0; jt < 2; ++jt){
                int col = wl*32 + jt*16 + lm;
                #pragma unroll
                for (int r = 0; r < 4; ++r){
                    int lrow = rt*16 + kq*4 + r;
                    float hv = bf2f(sm[8704 + lrow*136 + col]);
                    float g = 1.f/(1.f + expf(-accG[rt][jt][r]));
                    accO[rt][jt][r] = hv + s2*g*accO[rt][jt][r];
                }
            }
        __syncthreads();   // all H reads done; H region becomes h2 (bf16, stride 132)
        #pragma unroll
        for (int rt = 0; rt < 4; ++rt)
            #pragma unroll
            for (int jt = 0; jt < 2; ++jt){
                int col = wl*32 + jt*16 + lm;
                #pragma unroll
                for (int r = 0; r < 4; ++r)
                    sm[8704 + (rt*16+kq*4+r)*132 + col] = f2bf(accO[rt][jt][r]);
            }
        __syncthreads();
        // ---- RMS + mixture ----
        {
            int r = tt >> 2, q = tt & 3;
            size_t row = r0 + r;
            const u16* h2p = sm + 8704 + r*132 + q*32;
            float h2a[32], v0a[32], v1a[32];
            float ss0 = 0.f, ss1 = 0.f, ss2 = 0.f, q0 = 0.f, q1 = 0.f, q2 = 0.f;
            #pragma unroll
            for (int c4 = 0; c4 < 8; ++c4){
                uint2 hk = *(const uint2*)(h2p + c4*4);
                float4 a0 = *(const float4*)(hist0 + row*C_ + q*32 + c4*4);
                float4 a1 = *(const float4*)(hist1 + row*C_ + q*32 + c4*4);
                const u16* pu = (const u16*)&hk;
                const float* p0 = (const float*)&a0;
                const float* p1 = (const float*)&a1;
                #pragma unroll
                for (int e = 0; e < 4; ++e){
                    float bw = sLn[256 + q*32 + c4*4 + e];
                    float x2 = bf2f(pu[e]), x0 = p0[e], x1 = p1[e];
                    h2a[c4*4+e] = x2; v0a[c4*4+e] = x0; v1a[c4*4+e] = x1;
                    ss0 += x0*x0; ss1 += x1*x1; ss2 += x2*x2;
                    q0 += bw*x0; q1 += bw*x1; q2 += bw*x2;
                }
            }
            ss0 += __shfl_xor(ss0,1); ss0 += __shfl_xor(ss0,2);
            ss1 += __shfl_xor(ss1,1); ss1 += __shfl_xor(ss1,2);
            ss2 += __shfl_xor(ss2,1); ss2 += __shfl_xor(ss2,2);
            q0 += __shfl_xor(q0,1); q0 += __shfl_xor(q0,2);
            q1 += __shfl_xor(q1,1); q1 += __shfl_xor(q1,2);
            q2 += __shfl_xor(q2,1); q2 += __shfl_xor(q2,2);
            float i0 = rsqrtf(ss0*(1.f/128.f) + 1e-6f);
            float i1 = rsqrtf(ss1*(1.f/128.f) + 1e-6f);
            float i2 = rsqrtf(ss2*(1.f/128.f) + 1e-6f);
            float l0 = fminf(fmaxf(q0*i0, -30.f), 30.f);
            float l1 = fminf(fmaxf(q1*i1, -30.f), 30.f);
            float l2 = fminf(fmaxf(q2*i2, -30.f), 30.f);
            float mx = fmaxf(l0, fmaxf(l1, l2));
            float e0 = expf(l0-mx), e1 = expf(l1-mx), e2 = expf(l2-mx);
            float isum = 1.f/(e0+e1+e2);
            #pragma unroll
            for (int c4 = 0; c4 < 8; ++c4){
                float o[4];
                #pragma unroll
                for (int e = 0; e < 4; ++e){
                    int i = c4*4+e;
                    o[e] = (e0*v0a[i] + e1*v1a[i] + e2*h2a[i])*isum;
                }
                *(float4*)(outp + row*C_ + q*32 + c4*4) = *(float4*)o;
            }
        }
        __syncthreads();
    }
}

extern "C" void kernel_launch(void* const* d_in, const int* in_sizes, int n_in,
                              void* d_out, int out_size, void* d_ws, size_t ws_size,
                              hipStream_t stream){
    (void)in_sizes; (void)n_in; (void)out_size; (void)ws_size;
    const float* h     = (const float*)d_in[0];
    const float* hist0 = (const float*)d_in[1];
    const float* hist1 = (const float*)d_in[2];
    const float* dw_w  = (const float*)d_in[3];
    const float* pw_w  = (const float*)d_in[4];
    const float* gn_w  = (const float*)d_in[5];
    const float* gn_b  = (const float*)d_in[6];
    const float* gr1_s = (const float*)d_in[7];
    const float* gr1_gw= (const float*)d_in[8];
    const float* gr1_gb= (const float*)d_in[9];
    const float* gtok  = (const float*)d_in[10];
    const float* in_w  = (const float*)d_in[11];
    const float* in_b  = (const float*)d_in[12];
    const float* out_w = (const float*)d_in[13];
    const float* out_b = (const float*)d_in[14];
    const float* ln_w  = (const float*)d_in[15];
    const float* ln_b  = (const float*)d_in[16];
    const float* gr2_s = (const float*)d_in[17];
    const float* gr2_gw= (const float*)d_in[18];
    const float* gr2_gb= (const float*)d_in[19];
    const float* rms_w = (const float*)d_in[20];
    const float* blk_w = (const float*)d_in[21];
    float* out = (float*)d_out;

    u16* ybf  = (u16*)d_out;                        // B*N*C bf16
    u16* hb16 = (u16*)d_out + (size_t)B_*N_*C_;     // B*N*C bf16

    float* W = (float*)d_ws;
    size_t off = 0;
    float* gstats  = W + off; off += 128;
    float* gfin    = W + off; off += 128;
    float* qhT     = W + off; off += 3*128*64;
    float* o_mean  = W + off; off += 3*B_*M_*C_;
    float* tokens  = W + off; off += B_*M_*C_;
    float* t_in    = W + off; off += B_*M_*C_;
    float* qkv3    = W + off; off += B_*M_*384;
    float* o3      = W + off; off += B_*M_*C_;
    float* tokens2 = W + off; off += B_*M_*C_;
    u16* U = (u16*)(W + off);
    size_t uo = 0;
    u16* h1b = U + uo; uo += (size_t)B_*N_*C_;
    u16* wA  = U + uo; uo += 256*128;
    u16* wKV = U + uo; uo += 3*256*128;
    u16* wQ  = U + uo; uo += 128*128;
    u16* wO  = U + uo; uo += 128*128;
    u16* wG2 = U + uo; uo += 128*128;
    u16* khs = U + uo; uo += B_*4*64*32;
    u16* vhb = U + uo; uo += B_*64*128;

    hipMemsetAsync(gstats, 0, 128*sizeof(float), stream);
    hipMemsetAsync(o_mean, 0, 3*B_*M_*C_*sizeof(float), stream);
    k_wcvt<<<704, 256, 0, stream>>>(pw_w, gr1_gw, in_w, out_w, gr2_gw, wA, wKV, wQ, wO, wG2);
    k_conv3<<<1024, 256, 0, stream>>>(h, dw_w, ybf, hb16, gstats);
    k_gstats_fin<<<1, 64, 0, stream>>>(gstats, gfin);
    k_stageA<<<1024, 256, 0, stream>>>(ybf, hb16, gfin, gn_w, gn_b, gr1_gb, gr1_s, wA, h1b);
    k_qh_axes<<<96, 256, 0, stream>>>(gtok, in_w, in_b, qhT);
    k_axis_attn<0,64,2048><<<512, 256, 0, stream>>>(h1b, wKV, in_b, qhT, o_mean);
    k_axis_attn<1,64,2048><<<512, 256, 0, stream>>>(h1b, wKV, in_b, qhT, o_mean);
    k_axis_attn<2,32,4096><<<1024, 256, 0, stream>>>(h1b, wKV, in_b, qhT, o_mean);
    k_tokens<<<64, 256, 0, stream>>>(o_mean, out_w, out_b, tokens);
    k_ln<<<B_*M_, 128, 0, stream>>>(tokens, ln_w, ln_b, t_in);
    k_qkv3<<<192, 256, 0, stream>>>(t_in, in_w, in_b, qkv3);
    k_attn3<<<8, 64, 0, stream>>>(qkv3, o3);
    k_tokens2<<<64, 256, 0, stream>>>(o3, out_w, out_b, tokens2);
    k_kv4<<<128, 256, 0, stream>>>(tokens2, in_w, in_b, khs, vhb);
    k_globfinal<<<1024, 512, 0, stream>>>(h1b, wQ, wO, wG2, khs, vhb, in_b, out_b,
                                          gr2_gb, gr2_s, ln_w, ln_b, hist0, hist1, rms_w, blk_w, out);
}

// Round 11
// 1032.843 us; speedup vs baseline: 1.0920x; 1.0769x over previous
//
#include <hip/hip_runtime.h>
#include <hip/hip_bf16.h>

#define B_ 2
#define C_ 128
#define HX_ 64
#define HY_ 64
#define HZ_ 32
#define N_ 131072
#define M_ 64
#define G_ 32
#define SCALE_ 0.17677669529663687f  // 1/sqrt(32)

typedef unsigned short u16;
typedef __bf16 bf16x8 __attribute__((ext_vector_type(8)));
typedef float f32x4 __attribute__((ext_vector_type(4)));

#define MFMA(a, b, c) __builtin_amdgcn_mfma_f32_16x16x32_bf16(a, b, c, 0, 0, 0)

__device__ __forceinline__ float bf2f(u16 u){
    return __uint_as_float(((unsigned int)u) << 16);
}
__device__ __forceinline__ u16 f2bf(float f){
    unsigned int u = __float_as_uint(f);
    unsigned int r = (u + 0x7FFFu + ((u >> 16) & 1u)) >> 16;
    return (u16)r;
}
__device__ __forceinline__ bf16x8 ldf(const u16* p){
    return __builtin_bit_cast(bf16x8, *reinterpret_cast<const uint4*>(p));
}
__device__ __forceinline__ float wred_sum(float v){
    for (int o = 32; o; o >>= 1) v += __shfl_xor(v, o);
    return v;
}

// ---------------- weight conversion to bf16 ----------------
__global__ __launch_bounds__(256) void k_wcvt(const float* __restrict__ pw, const float* __restrict__ g1w,
        const float* __restrict__ in_w, const float* __restrict__ out_w, const float* __restrict__ g2w,
        u16* __restrict__ wA, u16* __restrict__ wKV, u16* __restrict__ wQ, u16* __restrict__ wO, u16* __restrict__ wG2){
    int idx = blockIdx.x*256 + threadIdx.x;
    if (idx < 32768){
        int j = idx >> 7, k = idx & 127;
        wA[idx] = f2bf(j < 128 ? pw[j*128 + k] : g1w[(j-128)*128 + k]);
    } else if (idx < 131072){
        int r = idx - 32768;
        int a = r >> 15, jk = r & 32767;
        int j = jk >> 7, k = jk & 127;
        wKV[r] = f2bf(in_w[((size_t)a*384 + 128 + j)*128 + k]);
    } else if (idx < 147456){
        int r = idx - 131072;
        wQ[r] = f2bf(in_w[4*384*128 + r]);
    } else if (idx < 163840){
        int r = idx - 147456;
        wO[r] = f2bf(out_w[4*128*128 + r]);
    } else if (idx < 180224){
        int r = idx - 163840;
        wG2[r] = f2bf(g2w[r]);
    }
}

// ---------------- depthwise conv3d, float4-vectorized z-sliding + group stats ----------------
__global__ __launch_bounds__(256, 2) void k_conv3(const float* __restrict__ h,
        const float* __restrict__ dw_w, u16* __restrict__ ybf, u16* __restrict__ hb16,
        float* __restrict__ gstats){
    int t = threadIdx.x;
    int lane = t & 31;            // channel quad == GN group
    int c4 = lane << 2;
    int xg = t >> 5;              // 0..7
    int bi = blockIdx.x;          // [0, B*64*8)
    int b = bi >> 9;
    int y = (bi >> 3) & 63;
    int x = ((bi & 7) << 3) | xg;
    const float* hb = h + (size_t)b*N_*C_;
    u16* yb = ybf + (size_t)b*N_*C_;
    u16* hbb = hb16 + (size_t)b*N_*C_;
    f32x4 wv[27];
    int off[9];
    #pragma unroll
    for (int dxi = 0; dxi < 3; ++dxi){
        #pragma unroll
        for (int dyi = 0; dyi < 3; ++dyi){
            int xr = x + dxi - 1, yr = y + dyi - 1;
            float m = (xr >= 0 && xr < HX_ && yr >= 0 && yr < HY_) ? 1.f : 0.f;
            int xx = min(max(xr, 0), HX_-1);
            int yy = min(max(yr, 0), HY_-1);
            off[dxi*3+dyi] = (yy*64 + xx)*128 + c4;
            #pragma unroll
            for (int dzi = 0; dzi < 3; ++dzi){
                int k = (dxi*3+dyi)*3+dzi;
                int wk = dxi*9 + dyi*3 + dzi;
                f32x4 wq;
                #pragma unroll
                for (int e = 0; e < 4; ++e) wq[e] = dw_w[(c4+e)*27 + wk] * m;
                wv[k] = wq;
            }
        }
    }
    f32x4 accA = {0,0,0,0}, accB = {0,0,0,0}, accC = {0,0,0,0};
    f32x4 sum4 = {0,0,0,0}, ss4 = {0,0,0,0};
    #pragma unroll 2
    for (int zp = 0; zp < 32; ++zp){
        size_t zb = (size_t)zp*524288;
        f32x4 v[9];
        #pragma unroll
        for (int j = 0; j < 9; ++j) v[j] = *(const f32x4*)(hb + zb + off[j]);
        {
            unsigned int p0 = (unsigned int)f2bf(v[4][0]) | ((unsigned int)f2bf(v[4][1]) << 16);
            unsigned int p1 = (unsigned int)f2bf(v[4][2]) | ((unsigned int)f2bf(v[4][3]) << 16);
            uint2 pk = {p0, p1};
            *(uint2*)(hbb + zb + off[4]) = pk;
        }
        f32x4 s0 = {0,0,0,0}, s1 = {0,0,0,0}, s2 = {0,0,0,0};
        #pragma unroll
        for (int j = 0; j < 9; ++j){
            s0 += v[j]*wv[j*3+0];
            s1 += v[j]*wv[j*3+1];
            s2 += v[j]*wv[j*3+2];
        }
        accA += s2; accB += s1; accC += s0;
        if (zp >= 1){
            f32x4 yv = accA;
            sum4 += yv; ss4 += yv*yv;
            unsigned int p0 = (unsigned int)f2bf(yv[0]) | ((unsigned int)f2bf(yv[1]) << 16);
            unsigned int p1 = (unsigned int)f2bf(yv[2]) | ((unsigned int)f2bf(yv[3]) << 16);
            uint2 pk = {p0, p1};
            *(uint2*)(yb + (size_t)(zp-1)*524288 + off[4]) = pk;
        }
        accA = accB; accB = accC; accC = (f32x4){0,0,0,0};
    }
    {
        f32x4 yv = accA;   // out(31)
        sum4 += yv; ss4 += yv*yv;
        unsigned int p0 = (unsigned int)f2bf(yv[0]) | ((unsigned int)f2bf(yv[1]) << 16);
        unsigned int p1 = (unsigned int)f2bf(yv[2]) | ((unsigned int)f2bf(yv[3]) << 16);
        uint2 pk = {p0, p1};
        *(uint2*)(yb + (size_t)31*524288 + off[4]) = pk;
    }
    float sum = sum4[0]+sum4[1]+sum4[2]+sum4[3];
    float ss  = ss4[0]+ss4[1]+ss4[2]+ss4[3];
    sum += __shfl_xor(sum, 32);
    ss  += __shfl_xor(ss, 32);
    if ((t & 32) == 0){
        atomicAdd(&gstats[(b*G_ + lane)*2 + 0], sum);
        atomicAdd(&gstats[(b*G_ + lane)*2 + 1], ss);
    }
}

__global__ void k_gstats_fin(const float* __restrict__ gstats, float* __restrict__ gfin){
    int t = threadIdx.x;
    if (t < B_*G_){
        const float cnt = 4.f * (float)N_;
        float mean = gstats[t*2] / cnt;
        float var  = gstats[t*2+1] / cnt - mean*mean;
        gfin[t*2]   = mean;
        gfin[t*2+1] = rsqrtf(var + 1e-5f);
    }
}

// ---------------- stage A: GN+GELU (fused) + pointwise + gate1 via MFMA ----------------
__global__ __launch_bounds__(256) void k_stageA(const u16* __restrict__ ybf, const u16* __restrict__ hb16,
        const float* __restrict__ gfin, const float* __restrict__ gn_w, const float* __restrict__ gn_b,
        const float* __restrict__ g1b, const float* __restrict__ s1p,
        const u16* __restrict__ wA, u16* __restrict__ h1b){
    __shared__ __align__(16) u16 sU[64*136];
    __shared__ __align__(16) u16 sH[64*136];
    __shared__ float sPar[384];
    int t = threadIdx.x;
    int w = t >> 6, l = t & 63, lm = l & 15, kq = l >> 4;
    if (t < 128){ sPar[t] = gn_w[t]; sPar[128+t] = gn_b[t]; sPar[256+t] = gfin[t]; }
    bf16x8 wUf[2][4], wGf[2][4];
    float gbias[2];
    #pragma unroll
    for (int jt = 0; jt < 2; ++jt){
        int j = w*32 + jt*16 + lm;
        gbias[jt] = g1b[j];
        #pragma unroll
        for (int ks = 0; ks < 4; ++ks){
            wUf[jt][ks] = ldf(wA + (size_t)j*128 + ks*32 + kq*8);
            wGf[jt][ks] = ldf(wA + (size_t)(128+j)*128 + ks*32 + kq*8);
        }
    }
    float s1 = s1p[0];
    __syncthreads();
    for (int it = 0; it < 4; ++it){
        int tile = blockIdx.x + it*1024;
        size_t r0 = (size_t)tile*64;
        int bsel = (tile >= 2048) ? 1 : 0;
        for (int pass = 0; pass < 4; ++pass){
            int cid = pass*256 + t;
            int row = cid >> 4, col8 = (cid & 15)*8;
            size_t gi = (r0 + row)*C_ + col8;
            uint4 yraw = *(const uint4*)(ybf + gi);
            uint4 hraw = *(const uint4*)(hb16 + gi);
            const u16* yp = (const u16*)&yraw;
            unsigned int pu[4];
            #pragma unroll
            for (int p2 = 0; p2 < 4; ++p2){
                u16 r2[2];
                #pragma unroll
                for (int e2 = 0; e2 < 2; ++e2){
                    int e = p2*2 + e2;
                    int ch = col8 + e;
                    int g = ch >> 2;
                    float mean = sPar[256 + (bsel*32+g)*2];
                    float inv  = sPar[256 + (bsel*32+g)*2 + 1];
                    float v = (bf2f(yp[e]) - mean)*inv*sPar[ch] + sPar[128+ch];
                    float u = 0.5f*v*(1.f + erff(v*0.70710678118654752f));
                    r2[e2] = f2bf(u);
                }
                pu[p2] = (unsigned int)r2[0] | ((unsigned int)r2[1] << 16);
            }
            *(uint4*)(sU + row*136 + col8) = *(uint4*)pu;
            *(uint4*)(sH + row*136 + col8) = hraw;
        }
        __syncthreads();
        f32x4 accU[4][2], accG[4][2];
        #pragma unroll
        for (int rt = 0; rt < 4; ++rt)
            #pragma unroll
            for (int jt = 0; jt < 2; ++jt){
                accU[rt][jt] = (f32x4){0.f,0.f,0.f,0.f};
                accG[rt][jt] = (f32x4){gbias[jt],gbias[jt],gbias[jt],gbias[jt]};
            }
        #pragma unroll
        for (int rt = 0; rt < 4; ++rt)
            #pragma unroll
            for (int ks = 0; ks < 4; ++ks){
                bf16x8 aU = ldf(sU + (rt*16+lm)*136 + ks*32 + kq*8);
                bf16x8 aH = ldf(sH + (rt*16+lm)*136 + ks*32 + kq*8);
                #pragma unroll
                for (int jt = 0; jt < 2; ++jt){
                    accU[rt][jt] = MFMA(aU, wUf[jt][ks], accU[rt][jt]);
                    accG[rt][jt] = MFMA(aH, wGf[jt][ks], accG[rt][jt]);
                }
            }
        #pragma unroll
        for (int rt = 0; rt < 4; ++rt)
            #pragma unroll
            for (int jt = 0; jt < 2; ++jt){
                int col = w*32 + jt*16 + lm;
                #pragma unroll
                for (int r = 0; r < 4; ++r){
                    int lrow = rt*16 + kq*4 + r;
                    float g = 1.f/(1.f + expf(-accG[rt][jt][r]));
                    float hv = bf2f(sH[lrow*136 + col]);
                    float h1v = hv + s1*g*accU[rt][jt][r];
                    h1b[(r0 + lrow)*C_ + col] = f2bf(h1v);
                }
            }
        __syncthreads();
    }
}

// ---------------- axis attention Q projection (tiny, fp32) ----------------
__global__ __launch_bounds__(256) void k_qh_axes(const float* __restrict__ gtok,
        const float* __restrict__ in_w, const float* __restrict__ in_b, float* __restrict__ qhT){
    int idx = blockIdx.x*256 + threadIdx.x;   // [0, 3*128*64)
    int m = idx & 63;
    int hd = (idx >> 6) & 127;
    int a = idx >> 13;
    float acc = in_b[a*384 + hd];
    const float* w = in_w + ((size_t)a*384 + hd)*C_;
    const float* q = gtok + (size_t)m*C_;
    for (int c = 0; c < C_; ++c) acc += q[c]*w[c];
    qhT[idx] = acc;
}

// ---------------- axis attentions: full-MFMA (kvproj + QK^T + PV) ----------------
template<int AXIS, int L, int S>
__global__ __launch_bounds__(256, 2) void k_axis_attn(const u16* __restrict__ h1b,
        const u16* __restrict__ wKVb, const float* __restrict__ in_b,
        const float* __restrict__ qhT, float* __restrict__ o_mean){
    constexpr int SLICES = 8;
    constexpr int PARTS = S / SLICES;
    constexpr int PSROW = L + 8;
    constexpr int PSZ = 64 * PSROW;
    constexpr int NT = L / 16;
    constexpr int KS = L / 32;
    __shared__ __align__(16) u16 sm[6*PSZ];
    int t = threadIdx.x;
    int w = t >> 6, l = t & 63, lm = l & 15, kq = l >> 4;
    int b = blockIdx.x / PARTS;
    int part = blockIdx.x % PARTS;
    u16* rows = sm;
    u16* kv   = sm + 2*PSZ;
    u16* vT   = sm + 4*PSZ;
    u16* Ps   = sm + w*PSZ;
    bf16x8 wf[4][4];
    float bias[4];
    #pragma unroll
    for (int jt = 0; jt < 4; ++jt){
        int j = w*64 + jt*16 + lm;
        bias[jt] = in_b[AXIS*384 + 128 + j];
        #pragma unroll
        for (int ks = 0; ks < 4; ++ks)
            wf[jt][ks] = ldf(wKVb + ((size_t)AXIS*256 + j)*128 + ks*32 + kq*8);
    }
    bf16x8 qf[4];
    #pragma unroll
    for (int mt = 0; mt < 4; ++mt){
        union { u16 u[8]; bf16x8 v; } tmp;
        #pragma unroll
        for (int e = 0; e < 8; ++e)
            tmp.u[e] = f2bf(qhT[(AXIS*C_ + w*32 + kq*8 + e)*64 + mt*16 + lm] * SCALE_);
        qf[mt] = tmp.v;
    }
    f32x4 oacc[4][2];
    #pragma unroll
    for (int mt = 0; mt < 4; ++mt)
        #pragma unroll
        for (int dt = 0; dt < 2; ++dt)
            oacc[mt][dt] = (f32x4){0.f,0.f,0.f,0.f};
    const u16* hb = h1b + (size_t)b*N_*C_;
    for (int si = 0; si < SLICES; ++si){
        int s = part*SLICES + si;
        for (int ci = t; ci < L*16; ci += 256){
            int p = ci >> 4, c8 = (ci & 15)*8;
            int n;
            if (AXIS == 0){ int yy = s >> 5, zz = s & 31; n = zz*4096 + yy*64 + p; }
            else if (AXIS == 1){ int xx = s >> 5, zz = s & 31; n = zz*4096 + p*64 + xx; }
            else { int xx = s >> 6, yy = s & 63; n = p*4096 + yy*64 + xx; }
            *(uint4*)(rows + p*136 + c8) = *(const uint4*)(hb + (size_t)n*C_ + c8);
        }
        __syncthreads();
        #pragma unroll
        for (int rt = 0; rt < NT; ++rt){
            f32x4 acc[4];
            #pragma unroll
            for (int jt = 0; jt < 4; ++jt) acc[jt] = (f32x4){bias[jt],bias[jt],bias[jt],bias[jt]};
            #pragma unroll
            for (int ks = 0; ks < 4; ++ks){
                bf16x8 a = ldf(rows + (rt*16+lm)*136 + ks*32 + kq*8);
                #pragma unroll
                for (int jt = 0; jt < 4; ++jt) acc[jt] = MFMA(a, wf[jt][ks], acc[jt]);
            }
            #pragma unroll
            for (int jt = 0; jt < 4; ++jt){
                int j = w*64 + jt*16 + lm;
                #pragma unroll
                for (int r = 0; r < 4; ++r){
                    int key = rt*16 + kq*4 + r;
                    if (w < 2) kv[key*136 + j] = f2bf(acc[jt][r]);
                    else       vT[(j-128)*PSROW + key] = f2bf(acc[jt][r]);
                }
            }
        }
        __syncthreads();
        f32x4 lacc[4][NT];
        #pragma unroll
        for (int mt = 0; mt < 4; ++mt)
            #pragma unroll
            for (int nt = 0; nt < NT; ++nt) lacc[mt][nt] = (f32x4){0.f,0.f,0.f,0.f};
        #pragma unroll
        for (int nt = 0; nt < NT; ++nt){
            bf16x8 kf = ldf(kv + (nt*16+lm)*136 + w*32 + kq*8);
            #pragma unroll
            for (int mt = 0; mt < 4; ++mt) lacc[mt][nt] = MFMA(qf[mt], kf, lacc[mt][nt]);
        }
        __syncthreads();
        #pragma unroll
        for (int mt = 0; mt < 4; ++mt){
            #pragma unroll
            for (int r = 0; r < 4; ++r){
                float mx = lacc[mt][0][r];
                #pragma unroll
                for (int nt = 1; nt < NT; ++nt) mx = fmaxf(mx, lacc[mt][nt][r]);
                mx = fmaxf(mx, __shfl_xor(mx,1));
                mx = fmaxf(mx, __shfl_xor(mx,2));
                mx = fmaxf(mx, __shfl_xor(mx,4));
                mx = fmaxf(mx, __shfl_xor(mx,8));
                float ev[NT]; float sum = 0.f;
                #pragma unroll
                for (int nt = 0; nt < NT; ++nt){ ev[nt] = expf(lacc[mt][nt][r] - mx); sum += ev[nt]; }
                sum += __shfl_xor(sum,1);
                sum += __shfl_xor(sum,2);
                sum += __shfl_xor(sum,4);
                sum += __shfl_xor(sum,8);
                float inv = 1.f/sum;
                #pragma unroll
                for (int nt = 0; nt < NT; ++nt)
                    Ps[(mt*16 + kq*4 + r)*PSROW + nt*16 + lm] = f2bf(ev[nt]*inv);
            }
        }
        #pragma unroll
        for (int ks = 0; ks < KS; ++ks){
            bf16x8 vb[2];
            #pragma unroll
            for (int dt = 0; dt < 2; ++dt)
                vb[dt] = ldf(vT + (w*32 + dt*16 + lm)*PSROW + ks*32 + kq*8);
            #pragma unroll
            for (int mt = 0; mt < 4; ++mt){
                bf16x8 pa = ldf(Ps + (mt*16+lm)*PSROW + ks*32 + kq*8);
                #pragma unroll
                for (int dt = 0; dt < 2; ++dt)
                    oacc[mt][dt] = MFMA(pa, vb[dt], oacc[mt][dt]);
            }
        }
        __syncthreads();
    }
    const float invS = 1.f / (float)S;
    float* om = o_mean + (size_t)(AXIS*B_ + b)*M_*C_;
    #pragma unroll
    for (int mt = 0; mt < 4; ++mt)
        #pragma unroll
        for (int dt = 0; dt < 2; ++dt)
            #pragma unroll
            for (int r = 0; r < 4; ++r){
                int m = mt*16 + kq*4 + r;
                int d = dt*16 + lm;
                atomicAdd(&om[m*C_ + w*32 + d], oacc[mt][dt][r]*invS);
            }
}

// ---------------- token chain (small, fp32) ----------------
__global__ __launch_bounds__(256) void k_tokens(const float* __restrict__ o_mean,
        const float* __restrict__ out_w, const float* __restrict__ out_b, float* __restrict__ tokens){
    int idx = blockIdx.x*256 + threadIdx.x;  // [0, B*M*C)
    int c = idx & 127;
    int m = (idx >> 7) & 63;
    int b = idx >> 13;
    float acc = 0.f;
    for (int a = 0; a < 3; ++a){
        const float* om = o_mean + ((size_t)(a*B_ + b)*M_ + m)*C_;
        const float* w = out_w + ((size_t)a*C_ + c)*C_;
        float s = out_b[a*C_ + c];
        for (int k = 0; k < C_; ++k) s += om[k]*w[k];
        acc += s;
    }
    tokens[idx] = acc;
}

__global__ __launch_bounds__(128) void k_ln(const float* __restrict__ in,
        const float* __restrict__ w, const float* __restrict__ b, float* __restrict__ out){
    int r = blockIdx.x;
    int c = threadIdx.x;
    float v = in[(size_t)r*C_ + c];
    __shared__ float red[4];
    float s = wred_sum(v), ss = wred_sum(v*v);
    int wv = c >> 6;
    if ((c & 63) == 0){ red[wv*2] = s; red[wv*2+1] = ss; }
    __syncthreads();
    float S = red[0] + red[2], SS = red[1] + red[3];
    float mean = S / 128.f;
    float var = SS / 128.f - mean*mean;
    out[(size_t)r*C_ + c] = (v - mean) * rsqrtf(var + 1e-5f) * w[c] + b[c];
}

__global__ __launch_bounds__(256) void k_qkv3(const float* __restrict__ t_in,
        const float* __restrict__ in_w, const float* __restrict__ in_b, float* __restrict__ qkv3){
    int idx = blockIdx.x*256 + threadIdx.x;  // [0, B*M*384)
    int j = idx % 384;
    int m = (idx / 384) & 63;
    int b = idx / (384*64);
    const float* x = t_in + ((size_t)b*64 + m)*C_;
    const float* w = in_w + ((size_t)3*384 + j)*C_;
    float acc = in_b[3*384 + j];
    for (int c = 0; c < C_; ++c) acc += x[c]*w[c];
    qkv3[idx] = acc;
}

__global__ __launch_bounds__(64) void k_attn3(const float* __restrict__ qkv3, float* __restrict__ o3){
    int b = blockIdx.x >> 2, hh = blockIdx.x & 3;
    int m = threadIdx.x;
    const float* base = qkv3 + (size_t)b*64*384;
    float q[32];
    #pragma unroll
    for (int d = 0; d < 32; ++d) q[d] = base[m*384 + hh*32 + d];
    float lg[64]; float mx = -1e30f;
    for (int mk = 0; mk < 64; ++mk){
        float acc = 0.f;
        #pragma unroll
        for (int d = 0; d < 32; ++d) acc += q[d] * base[mk*384 + 128 + hh*32 + d];
        acc *= SCALE_;
        lg[mk] = acc; mx = fmaxf(mx, acc);
    }
    float sum = 0.f;
    #pragma unroll
    for (int mk = 0; mk < 64; ++mk){ float e = expf(lg[mk]-mx); lg[mk] = e; sum += e; }
    float inv = 1.f/sum;
    float o[32];
    #pragma unroll
    for (int d = 0; d < 32; ++d) o[d] = 0.f;
    for (int mk = 0; mk < 64; ++mk){
        float al = lg[mk]*inv;
        #pragma unroll
        for (int d = 0; d < 32; ++d) o[d] += al * base[mk*384 + 256 + hh*32 + d];
    }
    #pragma unroll
    for (int d = 0; d < 32; ++d) o3[((size_t)b*64 + m)*C_ + hh*32 + d] = o[d];
}

__global__ __launch_bounds__(256) void k_tokens2(const float* __restrict__ o3,
        const float* __restrict__ out_w, const float* __restrict__ out_b, float* __restrict__ tokens2){
    int idx = blockIdx.x*256 + threadIdx.x;
    int c = idx & 127;
    int m = (idx >> 7) & 63;
    int b = idx >> 13;
    const float* x = o3 + ((size_t)b*64 + m)*C_;
    const float* w = out_w + ((size_t)3*C_ + c)*C_;
    float acc = out_b[3*C_ + c];
    for (int k = 0; k < C_; ++k) acc += x[k]*w[k];
    tokens2[idx] = acc;
}

// kh: [b][h][key][32d] bf16, pre-scaled by SCALE_.  vh: [b][key][128] bf16.
__global__ __launch_bounds__(256) void k_kv4(const float* __restrict__ tokens2,
        const float* __restrict__ in_w, const float* __restrict__ in_b,
        u16* __restrict__ khs, u16* __restrict__ vhb){
    int idx = blockIdx.x*256 + threadIdx.x;   // [0, B*16384)
    int b = idx >> 14;
    int r = idx & 16383;
    if (r < 8192){
        int hh = r >> 11, key = (r >> 5) & 63, d = r & 31;
        int hd = hh*32 + d;
        const float* x = tokens2 + ((size_t)b*64 + key)*C_;
        const float* w = in_w + ((size_t)4*384 + 128 + hd)*C_;
        float acc = in_b[4*384 + 128 + hd];
        for (int c = 0; c < C_; ++c) acc += x[c]*w[c];
        khs[(size_t)b*8192 + r] = f2bf(acc * SCALE_);
    } else {
        int rr = r - 8192;
        int key = rr >> 7, c = rr & 127;
        const float* x = tokens2 + ((size_t)b*64 + key)*C_;
        const float* w = in_w + ((size_t)4*384 + 256 + c)*C_;
        float acc = in_b[4*384 + 256 + c];
        for (int k = 0; k < 128; ++k) acc += x[k]*w[k];
        vhb[(size_t)b*8192 + rr] = f2bf(acc);
    }
}

// ---------------- glob attention: LN -> Qproj -> attn -> outproj+gate2 -> h2 (bf16) ----------------
// 256 threads, 1 tile of 64 rows per block (grid 4096). Register-slim: weight fragments
// loaded K-blocked from global (L2-hot) instead of held persistently -> target <=128 VGPR.
// LDS (u16): X/QO [0,8704) ; H/h2 [8704,17408) ; P [17408,22016)
__global__ __launch_bounds__(256, 4) void k_glob2(const u16* __restrict__ h1b,
        const u16* __restrict__ wQb, const u16* __restrict__ wOb, const u16* __restrict__ wG2b,
        const u16* __restrict__ khs, const u16* __restrict__ vhb,
        const float* __restrict__ in_b, const float* __restrict__ out_b,
        const float* __restrict__ g2b, const float* __restrict__ s2p,
        const float* __restrict__ ln_w, const float* __restrict__ ln_b,
        u16* __restrict__ h2b){
    __shared__ __align__(16) u16 sm[22016];
    __shared__ float sLn[256];
    int t = threadIdx.x;
    int w = t >> 6, l = t & 63, lm = l & 15, kq = l >> 4;
    if (t < 128){ sLn[t] = ln_w[128+t]; sLn[128+t] = ln_b[128+t]; }
    int tile = blockIdx.x;            // [0, 4096)
    int b = tile >> 11;
    size_t r0 = (size_t)tile * 64;
    int j0 = w*32 + lm, j1 = w*32 + 16 + lm;
    float s2 = s2p[0];
    __syncthreads();
    // ---- stage h1 (raw -> H) + LN (-> X) ----
    {
        int r = t >> 2, q = t & 3;
        const u16* src = h1b + (r0 + r)*C_ + q*32;
        uint4 raw[4];
        float v[32];
        float s = 0.f, ss = 0.f;
        #pragma unroll
        for (int c4 = 0; c4 < 4; ++c4){
            raw[c4] = *(const uint4*)(src + c4*8);
            const u16* pu = (const u16*)&raw[c4];
            #pragma unroll
            for (int e = 0; e < 8; ++e){ float x = bf2f(pu[e]); v[c4*8+e] = x; s += x; ss += x*x; }
        }
        s += __shfl_xor(s,1); s += __shfl_xor(s,2);
        ss += __shfl_xor(ss,1); ss += __shfl_xor(ss,2);
        float mean = s*(1.f/128.f);
        float inv = rsqrtf(ss*(1.f/128.f) - mean*mean + 1e-5f);
        #pragma unroll
        for (int c4 = 0; c4 < 4; ++c4){
            unsigned int o[4];
            #pragma unroll
            for (int p2 = 0; p2 < 4; ++p2){
                int c = q*32 + c4*8 + p2*2;
                u16 a0 = f2bf((v[c4*8+p2*2]   - mean)*inv*sLn[c]   + sLn[128+c]);
                u16 a1 = f2bf((v[c4*8+p2*2+1] - mean)*inv*sLn[c+1] + sLn[128+c+1]);
                o[p2] = (unsigned int)a0 | ((unsigned int)a1 << 16);
            }
            *(uint4*)(sm + 0    + r*136 + q*32 + c4*8) = *(uint4*)o;
            *(uint4*)(sm + 8704 + r*136 + q*32 + c4*8) = raw[c4];
        }
    }
    __syncthreads();
    // ---- q projection (K-blocked weight loads) ----
    f32x4 accQ[4][2];
    {
        float qb0 = in_b[4*384 + j0], qb1 = in_b[4*384 + j1];
        #pragma unroll
        for (int rt = 0; rt < 4; ++rt){
            accQ[rt][0] = (f32x4){qb0,qb0,qb0,qb0};
            accQ[rt][1] = (f32x4){qb1,qb1,qb1,qb1};
        }
    }
    #pragma unroll
    for (int ks = 0; ks < 4; ++ks){
        bf16x8 wq0 = ldf(wQb + (size_t)j0*128 + ks*32 + kq*8);
        bf16x8 wq1 = ldf(wQb + (size_t)j1*128 + ks*32 + kq*8);
        #pragma unroll
        for (int rt = 0; rt < 4; ++rt){
            bf16x8 a = ldf(sm + 0 + (rt*16+lm)*136 + ks*32 + kq*8);
            accQ[rt][0] = MFMA(a, wq0, accQ[rt][0]);
            accQ[rt][1] = MFMA(a, wq1, accQ[rt][1]);
        }
    }
    __syncthreads();   // all X reads done; X region becomes QO
    #pragma unroll
    for (int rt = 0; rt < 4; ++rt)
        #pragma unroll
        for (int jt = 0; jt < 2; ++jt)
            #pragma unroll
            for (int r = 0; r < 4; ++r)
                sm[0 + (rt*16+kq*4+r)*136 + w*32+jt*16+lm] = f2bf(accQ[rt][jt][r]);
    // ---- attn (wave = head; QO cols wave-private) ----
    {
        bf16x8 khf[4];
        #pragma unroll
        for (int jt = 0; jt < 4; ++jt)
            khf[jt] = ldf(khs + ((size_t)(b*4 + w)*64 + jt*16 + lm)*32 + kq*8);
        bf16x8 vf[2][2];
        #pragma unroll
        for (int jt = 0; jt < 2; ++jt)
            #pragma unroll
            for (int ks = 0; ks < 2; ++ks){
                union { u16 u[8]; bf16x8 v; } tmp;
                #pragma unroll
                for (int e = 0; e < 8; ++e){
                    int key = ks*32 + kq*8 + e;
                    tmp.u[e] = vhb[(size_t)(b*64 + key)*128 + w*32 + jt*16 + lm];
                }
                vf[jt][ks] = tmp.v;
            }
        u16* Ps = sm + 17408 + w*1152;
        #pragma unroll
        for (int mt = 0; mt < 4; ++mt){
            bf16x8 aq = ldf(sm + 0 + (mt*16+lm)*136 + w*32 + kq*8);
            f32x4 lacc[4];
            #pragma unroll
            for (int jt = 0; jt < 4; ++jt) lacc[jt] = (f32x4){0.f,0.f,0.f,0.f};
            #pragma unroll
            for (int jt = 0; jt < 4; ++jt) lacc[jt] = MFMA(aq, khf[jt], lacc[jt]);
            #pragma unroll
            for (int r = 0; r < 4; ++r){
                float v0 = lacc[0][r], v1 = lacc[1][r], v2 = lacc[2][r], v3 = lacc[3][r];
                float mx = fmaxf(fmaxf(v0,v1), fmaxf(v2,v3));
                mx = fmaxf(mx, __shfl_xor(mx,1));
                mx = fmaxf(mx, __shfl_xor(mx,2));
                mx = fmaxf(mx, __shfl_xor(mx,4));
                mx = fmaxf(mx, __shfl_xor(mx,8));
                float e0 = expf(v0-mx), e1 = expf(v1-mx), e2 = expf(v2-mx), e3 = expf(v3-mx);
                float sum = e0+e1+e2+e3;
                sum += __shfl_xor(sum,1);
                sum += __shfl_xor(sum,2);
                sum += __shfl_xor(sum,4);
                sum += __shfl_xor(sum,8);
                float inv = 1.f/sum;
                Ps[(kq*4+r)*72 + lm     ] = f2bf(e0*inv);
                Ps[(kq*4+r)*72 + lm + 16] = f2bf(e1*inv);
                Ps[(kq*4+r)*72 + lm + 32] = f2bf(e2*inv);
                Ps[(kq*4+r)*72 + lm + 48] = f2bf(e3*inv);
            }
            f32x4 of[2];
            #pragma unroll
            for (int jt = 0; jt < 2; ++jt) of[jt] = (f32x4){0.f,0.f,0.f,0.f};
            #pragma unroll
            for (int ks = 0; ks < 2; ++ks){
                bf16x8 ap = ldf(Ps + lm*72 + ks*32 + kq*8);
                #pragma unroll
                for (int jt = 0; jt < 2; ++jt)
                    of[jt] = MFMA(ap, vf[jt][ks], of[jt]);
            }
            #pragma unroll
            for (int jt = 0; jt < 2; ++jt)
                #pragma unroll
                for (int r = 0; r < 4; ++r)
                    sm[0 + (mt*16+kq*4+r)*136 + w*32+jt*16+lm] = f2bf(of[jt][r]);
        }
    }
    __syncthreads();
    // ---- out-proj (QO) + gate2 (H), K-blocked weight loads ----
    f32x4 accO[4][2], accG[4][2];
    {
        float ob0 = out_b[4*128 + j0], ob1 = out_b[4*128 + j1];
        float gb0 = g2b[j0], gb1 = g2b[j1];
        #pragma unroll
        for (int rt = 0; rt < 4; ++rt){
            accO[rt][0] = (f32x4){ob0,ob0,ob0,ob0};
            accO[rt][1] = (f32x4){ob1,ob1,ob1,ob1};
            accG[rt][0] = (f32x4){gb0,gb0,gb0,gb0};
            accG[rt][1] = (f32x4){gb1,gb1,gb1,gb1};
        }
    }
    #pragma unroll
    for (int ks = 0; ks < 4; ++ks){
        bf16x8 wo0 = ldf(wOb  + (size_t)j0*128 + ks*32 + kq*8);
        bf16x8 wo1 = ldf(wOb  + (size_t)j1*128 + ks*32 + kq*8);
        bf16x8 wg0 = ldf(wG2b + (size_t)j0*128 + ks*32 + kq*8);
        bf16x8 wg1 = ldf(wG2b + (size_t)j1*128 + ks*32 + kq*8);
        #pragma unroll
        for (int rt = 0; rt < 4; ++rt){
            bf16x8 ao = ldf(sm + 0    + (rt*16+lm)*136 + ks*32 + kq*8);
            bf16x8 ah = ldf(sm + 8704 + (rt*16+lm)*136 + ks*32 + kq*8);
            accO[rt][0] = MFMA(ao, wo0, accO[rt][0]);
            accO[rt][1] = MFMA(ao, wo1, accO[rt][1]);
            accG[rt][0] = MFMA(ah, wg0, accG[rt][0]);
            accG[rt][1] = MFMA(ah, wg1, accG[rt][1]);
        }
    }
    // residual: h2 = h1 + s2*sigmoid(G)*O  (reads H)
    #pragma unroll
    for (int rt = 0; rt < 4; ++rt)
        #pragma unroll
        for (int jt = 0; jt < 2; ++jt){
            int col = w*32 + jt*16 + lm;
            #pragma unroll
            for (int r = 0; r < 4; ++r){
                int lrow = rt*16 + kq*4 + r;
                float hv = bf2f(sm[8704 + lrow*136 + col]);
                float g = 1.f/(1.f + expf(-accG[rt][jt][r]));
                accO[rt][jt][r] = hv + s2*g*accO[rt][jt][r];
            }
        }
    __syncthreads();   // all H reads done; H region becomes h2 (bf16)
    #pragma unroll
    for (int rt = 0; rt < 4; ++rt)
        #pragma unroll
        for (int jt = 0; jt < 2; ++jt){
            int col = w*32 + jt*16 + lm;
            #pragma unroll
            for (int r = 0; r < 4; ++r)
                sm[8704 + (rt*16+kq*4+r)*136 + col] = f2bf(accO[rt][jt][r]);
        }
    __syncthreads();
    // ---- cooperative coalesced store of h2 ----
    {
        int r = t >> 2, q = t & 3;
        u16* dst = h2b + (r0 + r)*C_ + q*32;
        #pragma unroll
        for (int c4 = 0; c4 < 4; ++c4)
            *(uint4*)(dst + c4*8) = *(const uint4*)(sm + 8704 + r*136 + q*32 + c4*8);
    }
}

// ---------------- streaming finale: RMS-mixture of {hist0, hist1, h2} ----------------
__global__ __launch_bounds__(256) void k_final2(const u16* __restrict__ h2b,
        const float* __restrict__ hist0, const float* __restrict__ hist1,
        const float* __restrict__ rms_w, const float* __restrict__ blk_w,
        float* __restrict__ outp){
    __shared__ float sbw[128];
    int t = threadIdx.x;
    if (t < 128) sbw[t] = blk_w[t]*rms_w[t];
    __syncthreads();
    const int TOT = B_*N_*4;   // quarter-rows
    for (int idx = blockIdx.x*256 + t; idx < TOT; idx += gridDim.x*256){
        int r = idx >> 2, q = idx & 3;
        size_t row = r;
        const u16* h2p = h2b + row*C_ + q*32;
        float h2a[32], v0a[32], v1a[32];
        float ss0 = 0.f, ss1 = 0.f, ss2 = 0.f, q0 = 0.f, q1 = 0.f, q2 = 0.f;
        #pragma unroll
        for (int c4 = 0; c4 < 4; ++c4){
            uint4 hk = *(const uint4*)(h2p + c4*8);
            float4 a0 = *(const float4*)(hist0 + row*C_ + q*32 + c4*8);
            float4 a0b = *(const float4*)(hist0 + row*C_ + q*32 + c4*8 + 4);
            float4 a1 = *(const float4*)(hist1 + row*C_ + q*32 + c4*8);
            float4 a1b = *(const float4*)(hist1 + row*C_ + q*32 + c4*8 + 4);
            const u16* pu = (const u16*)&hk;
            const float* p0 = (const float*)&a0;
            const float* p0b = (const float*)&a0b;
            const float* p1 = (const float*)&a1;
            const float* p1b = (const float*)&a1b;
            #pragma unroll
            for (int e = 0; e < 8; ++e){
                int i = c4*8 + e;
                float bw = sbw[q*32 + i];
                float x2 = bf2f(pu[e]);
                float x0 = (e < 4) ? p0[e] : p0b[e-4];
                float x1 = (e < 4) ? p1[e] : p1b[e-4];
                h2a[i] = x2; v0a[i] = x0; v1a[i] = x1;
                ss0 += x0*x0; ss1 += x1*x1; ss2 += x2*x2;
                q0 += bw*x0; q1 += bw*x1; q2 += bw*x2;
            }
        }
        ss0 += __shfl_xor(ss0,1); ss0 += __shfl_xor(ss0,2);
        ss1 += __shfl_xor(ss1,1); ss1 += __shfl_xor(ss1,2);
        ss2 += __shfl_xor(ss2,1); ss2 += __shfl_xor(ss2,2);
        q0 += __shfl_xor(q0,1); q0 += __shfl_xor(q0,2);
        q1 += __shfl_xor(q1,1); q1 += __shfl_xor(q1,2);
        q2 += __shfl_xor(q2,1); q2 += __shfl_xor(q2,2);
        float i0 = rsqrtf(ss0*(1.f/128.f) + 1e-6f);
        float i1 = rsqrtf(ss1*(1.f/128.f) + 1e-6f);
        float i2 = rsqrtf(ss2*(1.f/128.f) + 1e-6f);
        float l0 = fminf(fmaxf(q0*i0, -30.f), 30.f);
        float l1 = fminf(fmaxf(q1*i1, -30.f), 30.f);
        float l2 = fminf(fmaxf(q2*i2, -30.f), 30.f);
        float mx = fmaxf(l0, fmaxf(l1, l2));
        float e0 = expf(l0-mx), e1 = expf(l1-mx), e2 = expf(l2-mx);
        float isum = 1.f/(e0+e1+e2);
        #pragma unroll
        for (int c4 = 0; c4 < 8; ++c4){
            float o[4];
            #pragma unroll
            for (int e = 0; e < 4; ++e){
                int i = c4*4+e;
                o[e] = (e0*v0a[i] + e1*v1a[i] + e2*h2a[i])*isum;
            }
            *(float4*)(outp + row*C_ + q*32 + c4*4) = *(float4*)o;
        }
    }
}

extern "C" void kernel_launch(void* const* d_in, const int* in_sizes, int n_in,
                              void* d_out, int out_size, void* d_ws, size_t ws_size,
                              hipStream_t stream){
    (void)in_sizes; (void)n_in; (void)out_size; (void)ws_size;
    const float* h     = (const float*)d_in[0];
    const float* hist0 = (const float*)d_in[1];
    const float* hist1 = (const float*)d_in[2];
    const float* dw_w  = (const float*)d_in[3];
    const float* pw_w  = (const float*)d_in[4];
    const float* gn_w  = (const float*)d_in[5];
    const float* gn_b  = (const float*)d_in[6];
    const float* gr1_s = (const float*)d_in[7];
    const float* gr1_gw= (const float*)d_in[8];
    const float* gr1_gb= (const float*)d_in[9];
    const float* gtok  = (const float*)d_in[10];
    const float* in_w  = (const float*)d_in[11];
    const float* in_b  = (const float*)d_in[12];
    const float* out_w = (const float*)d_in[13];
    const float* out_b = (const float*)d_in[14];
    const float* ln_w  = (const float*)d_in[15];
    const float* ln_b  = (const float*)d_in[16];
    const float* gr2_s = (const float*)d_in[17];
    const float* gr2_gw= (const float*)d_in[18];
    const float* gr2_gb= (const float*)d_in[19];
    const float* rms_w = (const float*)d_in[20];
    const float* blk_w = (const float*)d_in[21];
    float* out = (float*)d_out;

    u16* ybf  = (u16*)d_out;                        // B*N*C bf16
    u16* hb16 = (u16*)d_out + (size_t)B_*N_*C_;     // B*N*C bf16

    float* W = (float*)d_ws;
    size_t off = 0;
    float* gstats  = W + off; off += 128;
    float* gfin    = W + off; off += 128;
    float* qhT     = W + off; off += 3*128*64;
    float* o_mean  = W + off; off += 3*B_*M_*C_;
    float* tokens  = W + off; off += B_*M_*C_;
    float* t_in    = W + off; off += B_*M_*C_;
    float* qkv3    = W + off; off += B_*M_*384;
    float* o3      = W + off; off += B_*M_*C_;
    float* tokens2 = W + off; off += B_*M_*C_;
    u16* U = (u16*)(W + off);
    size_t uo = 0;
    u16* h1b = U + uo; uo += (size_t)B_*N_*C_;
    u16* h2b = U + uo; uo += (size_t)B_*N_*C_;
    u16* wA  = U + uo; uo += 256*128;
    u16* wKV = U + uo; uo += 3*256*128;
    u16* wQ  = U + uo; uo += 128*128;
    u16* wO  = U + uo; uo += 128*128;
    u16* wG2 = U + uo; uo += 128*128;
    u16* khs = U + uo; uo += B_*4*64*32;
    u16* vhb = U + uo; uo += B_*64*128;

    hipMemsetAsync(gstats, 0, 128*sizeof(float), stream);
    hipMemsetAsync(o_mean, 0, 3*B_*M_*C_*sizeof(float), stream);
    k_wcvt<<<704, 256, 0, stream>>>(pw_w, gr1_gw, in_w, out_w, gr2_gw, wA, wKV, wQ, wO, wG2);
    k_conv3<<<1024, 256, 0, stream>>>(h, dw_w, ybf, hb16, gstats);
    k_gstats_fin<<<1, 64, 0, stream>>>(gstats, gfin);
    k_stageA<<<1024, 256, 0, stream>>>(ybf, hb16, gfin, gn_w, gn_b, gr1_gb, gr1_s, wA, h1b);
    k_qh_axes<<<96, 256, 0, stream>>>(gtok, in_w, in_b, qhT);
    k_axis_attn<0,64,2048><<<512, 256, 0, stream>>>(h1b, wKV, in_b, qhT, o_mean);
    k_axis_attn<1,64,2048><<<512, 256, 0, stream>>>(h1b, wKV, in_b, qhT, o_mean);
    k_axis_attn<2,32,4096><<<1024, 256, 0, stream>>>(h1b, wKV, in_b, qhT, o_mean);
    k_tokens<<<64, 256, 0, stream>>>(o_mean, out_w, out_b, tokens);
    k_ln<<<B_*M_, 128, 0, stream>>>(tokens, ln_w, ln_b, t_in);
    k_qkv3<<<192, 256, 0, stream>>>(t_in, in_w, in_b, qkv3);
    k_attn3<<<8, 64, 0, stream>>>(qkv3, o3);
    k_tokens2<<<64, 256, 0, stream>>>(o3, out_w, out_b, tokens2);
    k_kv4<<<128, 256, 0, stream>>>(tokens2, in_w, in_b, khs, vhb);
    k_glob2<<<4096, 256, 0, stream>>>(h1b, wQ, wO, wG2, khs, vhb, in_b, out_b,
                                      gr2_gb, gr2_s, ln_w, ln_b, h2b);
    k_final2<<<2048, 256, 0, stream>>>(h2b, hist0, hist1, rms_w, blk_w, out);
}